// Round 2
// baseline (189.271 us; speedup 1.0000x reference)
//
#include <hip/hip_runtime.h>
#include <stdint.h>
#include <math.h>

// PhysicsForwardModel: B=2, Nz=Nx=128, Ly=Lx=512.
// out[b,t,l] = (1/3) * sum_j Cy[j,l] * sum_k cos(F[k,j]*t) * a[k] * (Cy[:, :128] x[b] Cy[:,128:256]^T)[k,j]
//              + std_b * N(0,1)  (JAX threefry key=42, partitionable counters, XLA erfinv)

#define THREADS 256
#define HALF_N 262144  // 512*512 = per-batch element count

// ---------------- ws layout (float offsets) ----------------
// Cy      [0       .. 262144)   512x512 DCT-II matrix (orthonormal scaling)
// G       [262144  .. 393216)   B x 128 x 512 : x[b] @ Bm^T
// M       [393216  .. 917504)   B x 512 x 512 : a[k] * Cy[:, :128] @ G
// F       [917504  .. 1179648)  512x512 radial frequency
// V       [1179648 .. 1703936)  t-major: (512, B, 512)
// partial [1703936 .. 1704960)  256 blocks x {s0,q0,s1,q1}
// stats   [1704960 .. 1704962)  std0, std1

__device__ __forceinline__ uint32_t rotl32(uint32_t v, int r) {
  return (v << r) | (v >> (32 - r));
}

// XLA ErfInv32 (Giles) -- must match reference's lax.erf_inv
__device__ __forceinline__ float erfinv_xla(float x) {
  float w = -log1pf(__fmul_rn(-x, x));
  float p;
  if (w < 5.0f) {
    w = w - 2.5f;
    p = 2.81022636e-08f;
    p = fmaf(p, w, 3.43273939e-07f);
    p = fmaf(p, w, -3.5233877e-06f);
    p = fmaf(p, w, -4.39150654e-06f);
    p = fmaf(p, w, 0.00021858087f);
    p = fmaf(p, w, -0.00125372503f);
    p = fmaf(p, w, -0.00417768164f);
    p = fmaf(p, w, 0.246640727f);
    p = fmaf(p, w, 1.50140941f);
  } else {
    w = __fsqrt_rn(w) - 3.0f;
    p = -0.000200214257f;
    p = fmaf(p, w, 0.000100950558f);
    p = fmaf(p, w, 0.00134934322f);
    p = fmaf(p, w, -0.00367342844f);
    p = fmaf(p, w, 0.00573950773f);
    p = fmaf(p, w, -0.0076224613f);
    p = fmaf(p, w, 0.00943887047f);
    p = fmaf(p, w, 1.00167406f);
    p = fmaf(p, w, 2.83297682f);
  }
  return p * x;
}

// Cy[k,n] = s[k]*2*cos(pi*(2n+1)*k/1024);  F[k,j] = sqrt(ky[k]^2+kx[j]^2)
__global__ void init_kernel(float* __restrict__ Cy, float* __restrict__ F) {
  int idx = blockIdx.x * THREADS + threadIdx.x;  // < 262144
  int k = idx >> 9;
  int n = idx & 511;
  float nf = (float)n, kf = (float)k;
  const float pi_f = 3.14159274101257324f;
  float t1 = __fmul_rn(pi_f, __fadd_rn(__fmul_rn(2.0f, nf), 1.0f));
  float t2 = __fmul_rn(t1, kf);
  float arg = t2 * (1.0f / 1024.0f);
  float s = (k == 0) ? (1.0f / __fsqrt_rn(2048.0f)) : 0.03125f;
  Cy[idx] = __fmul_rn(s, __fmul_rn(2.0f, cosf(arg)));

  const float w0 = 3.14159274101257324f / 512.0f;  // exact: pi_f * 2^-9
  float ky = __fmul_rn(kf, w0);
  float kx = __fmul_rn(nf, w0);
  F[idx] = __fsqrt_rn(__fadd_rn(__fmul_rn(ky, ky), __fmul_rn(kx, kx)));
}

// G[b,i,l] = sum_{j<128} x[b,i,j] * Cy[l, 128+j]
__global__ void gemm1_kernel(const float* __restrict__ x, const float* __restrict__ Cy,
                             float* __restrict__ G) {
  __shared__ float xs[128];
  int b = blockIdx.x >> 7;
  int i = blockIdx.x & 127;
  const float* xr = x + (b * 128 + i) * 128;
  if (threadIdx.x < 128) xs[threadIdx.x] = xr[threadIdx.x];
  __syncthreads();
  for (int l = threadIdx.x; l < 512; l += THREADS) {
    const float* crow = Cy + l * 512 + 128;
    float acc = 0.0f;
#pragma unroll 8
    for (int j = 0; j < 128; ++j) acc = fmaf(xs[j], crow[j], acc);
    G[(b * 128 + i) * 512 + l] = acc;
  }
}

// M[b,k,l] = Cy[k,0] * sum_{i<128} Cy[k,i] * G[b,i,l]
__global__ void gemm2_kernel(const float* __restrict__ Cy, const float* __restrict__ G,
                             float* __restrict__ M) {
  __shared__ float as_[128];
  int b = blockIdx.x >> 9;
  int k = blockIdx.x & 511;
  if (threadIdx.x < 128) as_[threadIdx.x] = Cy[k * 512 + threadIdx.x];
  __syncthreads();
  float ak = as_[0];
  const float* Gb = G + b * 128 * 512;
  for (int l = threadIdx.x; l < 512; l += THREADS) {
    float acc = 0.0f;
#pragma unroll 8
    for (int i = 0; i < 128; ++i) acc = fmaf(as_[i], Gb[i * 512 + l], acc);
    M[(b * 512 + k) * 512 + l] = __fmul_rn(ak, acc);
  }
}

// V[t,b,j] = sum_k cos(F[k,j]*t) * M[b,k,j]; each block: 4 t-values x 256 j's
#define TT 4
__global__ void stageB_kernel(const float* __restrict__ F, const float* __restrict__ M,
                              float* __restrict__ V) {
  int tblk = blockIdx.x >> 1;
  int j = ((blockIdx.x & 1) << 8) + threadIdx.x;
  int t0 = tblk * TT;
  float tf[TT];
#pragma unroll
  for (int tt = 0; tt < TT; ++tt) tf[tt] = (float)(t0 + tt);
  float acc0[TT] = {0.f, 0.f, 0.f, 0.f};
  float acc1[TT] = {0.f, 0.f, 0.f, 0.f};
  const float* M1 = M + HALF_N;
  for (int k = 0; k < 512; ++k) {
    float f  = F[(k << 9) + j];
    float m0 = M[(k << 9) + j];
    float m1 = M1[(k << 9) + j];
#pragma unroll
    for (int tt = 0; tt < TT; ++tt) {
      float ph = __cosf(__fmul_rn(f, tf[tt]));  // arg bit-matches ref's f32 F*t
      acc0[tt] = fmaf(ph, m0, acc0[tt]);
      acc1[tt] = fmaf(ph, m1, acc1[tt]);
    }
  }
#pragma unroll
  for (int tt = 0; tt < TT; ++tt) {
    V[((t0 + tt) << 10) + j]       = acc0[tt];
    V[((t0 + tt) << 10) + 512 + j] = acc1[tt];
  }
}

// out[b,t,l] = (1/3) * sum_j Cy[j,l] * V[t,b,j]; fused per-block sum/sumsq partials
#define TC 4
__global__ void stageC_kernel(const float* __restrict__ Cy, const float* __restrict__ V,
                              float* __restrict__ out, float* __restrict__ partial) {
  __shared__ float vs[TC * 1024];
  int tblk = blockIdx.x >> 1;
  int l = ((blockIdx.x & 1) << 8) + threadIdx.x;
  int t0 = tblk * TC;
  for (int idx = threadIdx.x; idx < TC * 1024; idx += THREADS)
    vs[idx] = V[(t0 << 10) + idx];  // contiguous: [tt][b][j]
  __syncthreads();
  float acc0[TC] = {0.f, 0.f, 0.f, 0.f};
  float acc1[TC] = {0.f, 0.f, 0.f, 0.f};
  for (int j = 0; j < 512; ++j) {
    float c = Cy[(j << 9) + l];
#pragma unroll
    for (int tt = 0; tt < TC; ++tt) {
      acc0[tt] = fmaf(c, vs[(tt << 10) + j], acc0[tt]);
      acc1[tt] = fmaf(c, vs[(tt << 10) + 512 + j], acc1[tt]);
    }
  }
  float s0 = 0.f, q0 = 0.f, s1 = 0.f, q1 = 0.f;
#pragma unroll
  for (int tt = 0; tt < TC; ++tt) {
    float p0 = acc0[tt] / 3.0f;
    float p1 = acc1[tt] / 3.0f;
    out[((t0 + tt) << 9) + l] = p0;
    out[HALF_N + ((t0 + tt) << 9) + l] = p1;
    s0 += p0; q0 = fmaf(p0, p0, q0);
    s1 += p1; q1 = fmaf(p1, p1, q1);
  }
  for (int off = 32; off > 0; off >>= 1) {
    s0 += __shfl_down(s0, off);
    q0 += __shfl_down(q0, off);
    s1 += __shfl_down(s1, off);
    q1 += __shfl_down(q1, off);
  }
  __shared__ float red[4][4];
  int wave = threadIdx.x >> 6;
  if ((threadIdx.x & 63) == 0) {
    red[wave][0] = s0; red[wave][1] = q0; red[wave][2] = s1; red[wave][3] = q1;
  }
  __syncthreads();
  if (threadIdx.x == 0) {
    float a0 = 0.f, a1 = 0.f, a2 = 0.f, a3 = 0.f;
    for (int wv = 0; wv < 4; ++wv) {
      a0 += red[wv][0]; a1 += red[wv][1]; a2 += red[wv][2]; a3 += red[wv][3];
    }
    partial[blockIdx.x * 4 + 0] = a0;
    partial[blockIdx.x * 4 + 1] = a1;
    partial[blockIdx.x * 4 + 2] = a2;
    partial[blockIdx.x * 4 + 3] = a3;
  }
}

// reduce 256 block-partials -> std per batch (population std, matches jnp.std)
__global__ void stats_kernel(const float* __restrict__ partial, float* __restrict__ stats) {
  float s0 = partial[threadIdx.x * 4 + 0];
  float q0 = partial[threadIdx.x * 4 + 1];
  float s1 = partial[threadIdx.x * 4 + 2];
  float q1 = partial[threadIdx.x * 4 + 3];
  for (int off = 32; off > 0; off >>= 1) {
    s0 += __shfl_down(s0, off);
    q0 += __shfl_down(q0, off);
    s1 += __shfl_down(s1, off);
    q1 += __shfl_down(q1, off);
  }
  __shared__ float red[4][4];
  int wave = threadIdx.x >> 6;
  if ((threadIdx.x & 63) == 0) {
    red[wave][0] = s0; red[wave][1] = q0; red[wave][2] = s1; red[wave][3] = q1;
  }
  __syncthreads();
  if (threadIdx.x == 0) {
    float S = 0.f, Q = 0.f, S2 = 0.f, Q2 = 0.f;
    for (int wv = 0; wv < 4; ++wv) {
      S += red[wv][0]; Q += red[wv][1]; S2 += red[wv][2]; Q2 += red[wv][3];
    }
    const float invN = 1.0f / 262144.0f;
    float m0 = S * invN, m1 = S2 * invN;
    stats[0] = __fsqrt_rn(fmaxf(Q * invN - m0 * m0, 0.0f));
    stats[1] = __fsqrt_rn(fmaxf(Q2 * invN - m1 * m1, 0.0f));
  }
}

// JAX threefry, PARTITIONABLE scheme (jax_threefry_partitionable=True default):
// element i: threefry2x32(key=(0,42), counter=(i>>32, i&0xffffffff)) -> (o0,o1),
// 32-bit draw = o0 ^ o1. Here size < 2^32 so counter = (0, i).
__global__ void noise_kernel(float* __restrict__ out, const float* __restrict__ stats) {
  int i = blockIdx.x * THREADS + threadIdx.x;  // < 524288
  uint32_t x0 = 0u;
  uint32_t x1 = (uint32_t)i;
  const uint32_t k0 = 0u, k1 = 42u;
  const uint32_t k2 = k0 ^ k1 ^ 0x1BD11BDAu;
  x0 += k0; x1 += k1;
#define QR(r) x0 += x1; x1 = rotl32(x1, r); x1 ^= x0;
  QR(13) QR(15) QR(26) QR(6)
  x0 += k1; x1 += k2 + 1u;
  QR(17) QR(29) QR(16) QR(24)
  x0 += k2; x1 += k0 + 2u;
  QR(13) QR(15) QR(26) QR(6)
  x0 += k0; x1 += k1 + 3u;
  QR(17) QR(29) QR(16) QR(24)
  x0 += k1; x1 += k2 + 4u;
  QR(13) QR(15) QR(26) QR(6)
  x0 += k2; x1 += k0 + 5u;
#undef QR
  uint32_t bits = x0 ^ x1;
  // bits -> uniform[lo, 1): ((bits>>9)|1.0f) - 1, then *2.0f + lo (x2 exact), clamp
  const float lo = __uint_as_float(0xBF7FFFFFu);  // nextafter(-1,0)
  float f = __uint_as_float((bits >> 9) | 0x3F800000u) - 1.0f;
  float u = fmaxf(lo, __fadd_rn(__fmul_rn(f, 2.0f), lo));
  const float sqrt2 = 1.41421356237309515f;
  out[i] += stats[i >> 18] * (sqrt2 * erfinv_xla(u));
}

extern "C" void kernel_launch(void* const* d_in, const int* in_sizes, int n_in,
                              void* d_out, int out_size, void* d_ws, size_t ws_size,
                              hipStream_t stream) {
  const float* x = (const float*)d_in[0];
  float* ws = (float*)d_ws;
  float* Cy      = ws;
  float* G       = ws + 262144;
  float* M       = ws + 393216;
  float* F       = ws + 917504;
  float* V       = ws + 1179648;
  float* partial = ws + 1703936;
  float* stats   = ws + 1704960;
  float* out = (float*)d_out;

  init_kernel<<<1024, THREADS, 0, stream>>>(Cy, F);
  gemm1_kernel<<<256, THREADS, 0, stream>>>(x, Cy, G);
  gemm2_kernel<<<1024, THREADS, 0, stream>>>(Cy, G, M);
  stageB_kernel<<<256, THREADS, 0, stream>>>(F, M, V);
  stageC_kernel<<<256, THREADS, 0, stream>>>(Cy, V, out, partial);
  stats_kernel<<<1, THREADS, 0, stream>>>(partial, stats);
  noise_kernel<<<2048, THREADS, 0, stream>>>(out, stats);
}

// Round 3
// 161.466 us; speedup vs baseline: 1.1722x; 1.1722x over previous
//
#include <hip/hip_runtime.h>
#include <stdint.h>
#include <math.h>

// PhysicsForwardModel: B=2, Nz=Nx=128, Ly=Lx=512.
// out[b,t,l] = (1/3) * sum_j Cy[j,l] * sum_k cos(F[k,j]*t) * a[k] * (Cy[:, :128] x[b] Cy[:,128:256]^T)[k,j]
//              + std_b * N(0,1)  (JAX threefry key=42, partitionable counters, XLA erfinv)

#define THREADS 256
#define HALF_N 262144  // 512*512 = per-batch element count

// ---------------- ws layout (float offsets) ----------------
// Cy      [0       .. 262144)   512x512 DCT-II matrix
// G       [262144  .. 393216)   B x 128 x 512 (dead after gemm2; tail reused for partial/stats)
// partial [262144  .. 264192)   512 blocks x {s0,q0,s1,q1}   (overlays G, written after G is dead)
// stats   [264192  .. 264194)   std0, std1
// Mt      [393216  .. 917504)   B x 512(l) x 512(k) : transposed M, k contiguous
// F       [917504  .. 1179648)  512x512 radial frequency (symmetric!)
// V       [1179648 .. 1703936)  t-major: (512, B, 512)

__device__ __forceinline__ uint32_t rotl32(uint32_t v, int r) {
  return (v << r) | (v >> (32 - r));
}

// XLA ErfInv32 (Giles) -- matches reference's lax.erf_inv
__device__ __forceinline__ float erfinv_xla(float x) {
  float w = -log1pf(__fmul_rn(-x, x));
  float p;
  if (w < 5.0f) {
    w = w - 2.5f;
    p = 2.81022636e-08f;
    p = fmaf(p, w, 3.43273939e-07f);
    p = fmaf(p, w, -3.5233877e-06f);
    p = fmaf(p, w, -4.39150654e-06f);
    p = fmaf(p, w, 0.00021858087f);
    p = fmaf(p, w, -0.00125372503f);
    p = fmaf(p, w, -0.00417768164f);
    p = fmaf(p, w, 0.246640727f);
    p = fmaf(p, w, 1.50140941f);
  } else {
    w = __fsqrt_rn(w) - 3.0f;
    p = -0.000200214257f;
    p = fmaf(p, w, 0.000100950558f);
    p = fmaf(p, w, 0.00134934322f);
    p = fmaf(p, w, -0.00367342844f);
    p = fmaf(p, w, 0.00573950773f);
    p = fmaf(p, w, -0.0076224613f);
    p = fmaf(p, w, 0.00943887047f);
    p = fmaf(p, w, 1.00167406f);
    p = fmaf(p, w, 2.83297682f);
  }
  return p * x;
}

// Cy[k,n] = s[k]*2*cos(pi*(2n+1)*k/1024);  F[k,j] = sqrt(ky[k]^2+kx[j]^2)
__global__ void init_kernel(float* __restrict__ Cy, float* __restrict__ F) {
  int idx = blockIdx.x * THREADS + threadIdx.x;  // < 262144
  int k = idx >> 9;
  int n = idx & 511;
  float nf = (float)n, kf = (float)k;
  const float pi_f = 3.14159274101257324f;
  float t1 = __fmul_rn(pi_f, __fadd_rn(__fmul_rn(2.0f, nf), 1.0f));
  float t2 = __fmul_rn(t1, kf);
  float arg = t2 * (1.0f / 1024.0f);
  float s = (k == 0) ? (1.0f / __fsqrt_rn(2048.0f)) : 0.03125f;
  Cy[idx] = __fmul_rn(s, __fmul_rn(2.0f, cosf(arg)));

  const float w0 = 3.14159274101257324f / 512.0f;  // exact: pi_f * 2^-9
  float ky = __fmul_rn(kf, w0);
  float kx = __fmul_rn(nf, w0);
  F[idx] = __fsqrt_rn(__fadd_rn(__fmul_rn(ky, ky), __fmul_rn(kx, kx)));
}

// G[b,i,l] = sum_{j<128} x[b,i,j] * Cy[l, 128+j]
__global__ void gemm1_kernel(const float* __restrict__ x, const float* __restrict__ Cy,
                             float* __restrict__ G) {
  __shared__ float xs[128];
  int b = blockIdx.x >> 7;
  int i = blockIdx.x & 127;
  const float* xr = x + (b * 128 + i) * 128;
  if (threadIdx.x < 128) xs[threadIdx.x] = xr[threadIdx.x];
  __syncthreads();
  for (int l = threadIdx.x; l < 512; l += THREADS) {
    const float* crow = Cy + l * 512 + 128;
    float acc = 0.0f;
#pragma unroll 8
    for (int j = 0; j < 128; ++j) acc = fmaf(xs[j], crow[j], acc);
    G[(b * 128 + i) * 512 + l] = acc;
  }
}

// Mt[b,l,k] = Cy[k,0] * sum_{i<128} Cy[k,i] * G[b,i,l]   (transposed store: k contiguous)
__global__ void gemm2_kernel(const float* __restrict__ Cy, const float* __restrict__ G,
                             float* __restrict__ Mt) {
  __shared__ float as_[128];
  int b = blockIdx.x >> 9;
  int k = blockIdx.x & 511;
  if (threadIdx.x < 128) as_[threadIdx.x] = Cy[k * 512 + threadIdx.x];
  __syncthreads();
  float ak = as_[0];
  const float* Gb = G + b * 128 * 512;
  for (int l = threadIdx.x; l < 512; l += THREADS) {
    float acc = 0.0f;
#pragma unroll 8
    for (int i = 0; i < 128; ++i) acc = fmaf(as_[i], Gb[i * 512 + l], acc);
    Mt[(b * 512 + l) * 512 + k] = __fmul_rn(ak, acc);  // scattered 4B store, ~2us total
  }
}

// V[t,b,j] = sum_k cos(F[j,k]*t) * Mt[b,j,k]   (F symmetric: F[k,j]=F[j,k])
// Block = one j column; thread = t. F/Mt streams are wave-uniform -> scalar s_load chunks.
__global__ __launch_bounds__(512) void stageB_kernel(const float* __restrict__ F,
                                                     const float* __restrict__ Mt,
                                                     float* __restrict__ V) {
  int j = blockIdx.x;
  float tf = (float)threadIdx.x;
  const float* Fr = F + (j << 9);
  const float* M0 = Mt + (j << 9);
  const float* M1 = Mt + ((512 + j) << 9);
  float acc0 = 0.f, acc1 = 0.f;
#pragma unroll 8
  for (int k = 0; k < 512; ++k) {
    float ph = __cosf(__fmul_rn(Fr[k], tf));  // arg bit-matches ref's f32 F*t
    acc0 = fmaf(ph, M0[k], acc0);
    acc1 = fmaf(ph, M1[k], acc1);
  }
  int t = threadIdx.x;
  V[(t << 10) + j] = acc0;
  V[(t << 10) + 512 + j] = acc1;
}

// out[b,t,l] = (1/3) * sum_j Cy[j,l] * V[t,b,j]; V streams wave-uniform (scalar),
// Cy streamed coalesced. TC=2 t-rows per block, l-half per block -> grid 512.
#define TC 2
__global__ __launch_bounds__(256) void stageC_kernel(const float* __restrict__ Cy,
                                                     const float* __restrict__ V,
                                                     float* __restrict__ out,
                                                     float* __restrict__ partial) {
  int tblk = blockIdx.x >> 1;
  int l = ((blockIdx.x & 1) << 8) + threadIdx.x;
  int t0 = tblk * TC;
  const float* v00 = V + (t0 << 10);
  const float* v01 = v00 + 512;
  const float* v10 = V + ((t0 + 1) << 10);
  const float* v11 = v10 + 512;
  float a00 = 0.f, a01 = 0.f, a10 = 0.f, a11 = 0.f;
#pragma unroll 8
  for (int j = 0; j < 512; ++j) {
    float c = Cy[(j << 9) + l];
    a00 = fmaf(c, v00[j], a00);
    a01 = fmaf(c, v01[j], a01);
    a10 = fmaf(c, v10[j], a10);
    a11 = fmaf(c, v11[j], a11);
  }
  float p00 = a00 / 3.0f, p01 = a01 / 3.0f, p10 = a10 / 3.0f, p11 = a11 / 3.0f;
  out[(t0 << 9) + l] = p00;
  out[((t0 + 1) << 9) + l] = p10;
  out[HALF_N + (t0 << 9) + l] = p01;
  out[HALF_N + ((t0 + 1) << 9) + l] = p11;
  float s0 = p00 + p10, q0 = fmaf(p00, p00, p10 * p10);
  float s1 = p01 + p11, q1 = fmaf(p01, p01, p11 * p11);
  for (int off = 32; off > 0; off >>= 1) {
    s0 += __shfl_down(s0, off);
    q0 += __shfl_down(q0, off);
    s1 += __shfl_down(s1, off);
    q1 += __shfl_down(q1, off);
  }
  __shared__ float red[4][4];
  int wave = threadIdx.x >> 6;
  if ((threadIdx.x & 63) == 0) {
    red[wave][0] = s0; red[wave][1] = q0; red[wave][2] = s1; red[wave][3] = q1;
  }
  __syncthreads();
  if (threadIdx.x == 0) {
    float a0 = 0.f, a1 = 0.f, a2 = 0.f, a3 = 0.f;
    for (int wv = 0; wv < 4; ++wv) {
      a0 += red[wv][0]; a1 += red[wv][1]; a2 += red[wv][2]; a3 += red[wv][3];
    }
    partial[blockIdx.x * 4 + 0] = a0;
    partial[blockIdx.x * 4 + 1] = a1;
    partial[blockIdx.x * 4 + 2] = a2;
    partial[blockIdx.x * 4 + 3] = a3;
  }
}

// reduce 512 block-partials -> std per batch (population std, matches jnp.std)
__global__ __launch_bounds__(512) void stats_kernel(const float* __restrict__ partial,
                                                    float* __restrict__ stats) {
  float s0 = partial[threadIdx.x * 4 + 0];
  float q0 = partial[threadIdx.x * 4 + 1];
  float s1 = partial[threadIdx.x * 4 + 2];
  float q1 = partial[threadIdx.x * 4 + 3];
  for (int off = 32; off > 0; off >>= 1) {
    s0 += __shfl_down(s0, off);
    q0 += __shfl_down(q0, off);
    s1 += __shfl_down(s1, off);
    q1 += __shfl_down(q1, off);
  }
  __shared__ float red[8][4];
  int wave = threadIdx.x >> 6;
  if ((threadIdx.x & 63) == 0) {
    red[wave][0] = s0; red[wave][1] = q0; red[wave][2] = s1; red[wave][3] = q1;
  }
  __syncthreads();
  if (threadIdx.x == 0) {
    float S = 0.f, Q = 0.f, S2 = 0.f, Q2 = 0.f;
    for (int wv = 0; wv < 8; ++wv) {
      S += red[wv][0]; Q += red[wv][1]; S2 += red[wv][2]; Q2 += red[wv][3];
    }
    const float invN = 1.0f / 262144.0f;
    float m0 = S * invN, m1 = S2 * invN;
    stats[0] = __fsqrt_rn(fmaxf(Q * invN - m0 * m0, 0.0f));
    stats[1] = __fsqrt_rn(fmaxf(Q2 * invN - m1 * m1, 0.0f));
  }
}

// JAX threefry, partitionable: element i -> threefry2x32(key=(0,42), ctr=(0,i)), bits=o0^o1
__global__ void noise_kernel(float* __restrict__ out, const float* __restrict__ stats) {
  int i = blockIdx.x * THREADS + threadIdx.x;  // < 524288
  uint32_t x0 = 0u;
  uint32_t x1 = (uint32_t)i;
  const uint32_t k0 = 0u, k1 = 42u;
  const uint32_t k2 = k0 ^ k1 ^ 0x1BD11BDAu;
  x0 += k0; x1 += k1;
#define QR(r) x0 += x1; x1 = rotl32(x1, r); x1 ^= x0;
  QR(13) QR(15) QR(26) QR(6)
  x0 += k1; x1 += k2 + 1u;
  QR(17) QR(29) QR(16) QR(24)
  x0 += k2; x1 += k0 + 2u;
  QR(13) QR(15) QR(26) QR(6)
  x0 += k0; x1 += k1 + 3u;
  QR(17) QR(29) QR(16) QR(24)
  x0 += k1; x1 += k2 + 4u;
  QR(13) QR(15) QR(26) QR(6)
  x0 += k2; x1 += k0 + 5u;
#undef QR
  uint32_t bits = x0 ^ x1;
  const float lo = __uint_as_float(0xBF7FFFFFu);  // nextafter(-1,0)
  float f = __uint_as_float((bits >> 9) | 0x3F800000u) - 1.0f;
  float u = fmaxf(lo, __fadd_rn(__fmul_rn(f, 2.0f), lo));
  const float sqrt2 = 1.41421356237309515f;
  out[i] += stats[i >> 18] * (sqrt2 * erfinv_xla(u));
}

extern "C" void kernel_launch(void* const* d_in, const int* in_sizes, int n_in,
                              void* d_out, int out_size, void* d_ws, size_t ws_size,
                              hipStream_t stream) {
  const float* x = (const float*)d_in[0];
  float* ws = (float*)d_ws;
  float* Cy      = ws;
  float* G       = ws + 262144;
  float* partial = ws + 262144;  // overlays G (G dead after gemm2, partial written in stageC)
  float* stats   = ws + 264192;
  float* Mt      = ws + 393216;
  float* F       = ws + 917504;
  float* V       = ws + 1179648;
  float* out = (float*)d_out;

  init_kernel<<<1024, THREADS, 0, stream>>>(Cy, F);
  gemm1_kernel<<<256, THREADS, 0, stream>>>(x, Cy, G);
  gemm2_kernel<<<1024, THREADS, 0, stream>>>(Cy, G, Mt);
  stageB_kernel<<<512, 512, 0, stream>>>(F, Mt, V);
  stageC_kernel<<<512, THREADS, 0, stream>>>(Cy, V, out, partial);
  stats_kernel<<<1, 512, 0, stream>>>(partial, stats);
  noise_kernel<<<2048, THREADS, 0, stream>>>(out, stats);
}

// Round 4
// 153.994 us; speedup vs baseline: 1.2291x; 1.0485x over previous
//
#include <hip/hip_runtime.h>
#include <stdint.h>
#include <math.h>

// PhysicsForwardModel: B=2, Nz=Nx=128, Ly=Lx=512.
// out[b,t,l] = (1/3) * sum_j Cy[j,l] * sum_k cos(F[k,j]*t) * a[k] * (Cy[:, :128] x[b] Cy[:,128:256]^T)[k,j]
//              + std_b * N(0,1)  (JAX threefry key=42, partitionable counters, XLA erfinv)

#define THREADS 256
#define HALF_N 262144  // 512*512 = per-batch element count

// ---------------- ws layout (float offsets) ----------------
// Cy      [0       .. 262144)   512x512 DCT-II matrix
// G       [262144  .. 393216)   B x 128 x 512 (dead after gemm2)
// partial [262144  .. 264192)   512 blocks x {s0,q0,s1,q1}   (overlays dead G)
// stats   [264192  .. 264194)   std0, std1
// Mt      [393216  .. 917504)   B x 512(l) x 512(k) : transposed M, k contiguous
// F       [917504  .. 1179648)  512x512 radial frequency (symmetric)
// Vt      [1179648 .. 1703936)  [j][b][t] : 512 x 2 x 512, t contiguous

__device__ __forceinline__ uint32_t rotl32(uint32_t v, int r) {
  return (v << r) | (v >> (32 - r));
}

// XLA ErfInv32 (Giles) -- matches reference's lax.erf_inv
__device__ __forceinline__ float erfinv_xla(float x) {
  float w = -log1pf(__fmul_rn(-x, x));
  float p;
  if (w < 5.0f) {
    w = w - 2.5f;
    p = 2.81022636e-08f;
    p = fmaf(p, w, 3.43273939e-07f);
    p = fmaf(p, w, -3.5233877e-06f);
    p = fmaf(p, w, -4.39150654e-06f);
    p = fmaf(p, w, 0.00021858087f);
    p = fmaf(p, w, -0.00125372503f);
    p = fmaf(p, w, -0.00417768164f);
    p = fmaf(p, w, 0.246640727f);
    p = fmaf(p, w, 1.50140941f);
  } else {
    w = __fsqrt_rn(w) - 3.0f;
    p = -0.000200214257f;
    p = fmaf(p, w, 0.000100950558f);
    p = fmaf(p, w, 0.00134934322f);
    p = fmaf(p, w, -0.00367342844f);
    p = fmaf(p, w, 0.00573950773f);
    p = fmaf(p, w, -0.0076224613f);
    p = fmaf(p, w, 0.00943887047f);
    p = fmaf(p, w, 1.00167406f);
    p = fmaf(p, w, 2.83297682f);
  }
  return p * x;
}

// Cy[k,n] = s[k]*2*cos(pi*(2n+1)*k/1024);  F[k,j] = sqrt(ky[k]^2+kx[j]^2)
__global__ void init_kernel(float* __restrict__ Cy, float* __restrict__ F) {
  int idx = blockIdx.x * THREADS + threadIdx.x;  // < 262144
  int k = idx >> 9;
  int n = idx & 511;
  float nf = (float)n, kf = (float)k;
  const float pi_f = 3.14159274101257324f;
  float t1 = __fmul_rn(pi_f, __fadd_rn(__fmul_rn(2.0f, nf), 1.0f));
  float t2 = __fmul_rn(t1, kf);
  float arg = t2 * (1.0f / 1024.0f);
  float s = (k == 0) ? (1.0f / __fsqrt_rn(2048.0f)) : 0.03125f;
  Cy[idx] = __fmul_rn(s, __fmul_rn(2.0f, cosf(arg)));

  const float w0 = 3.14159274101257324f / 512.0f;  // exact: pi_f * 2^-9
  float ky = __fmul_rn(kf, w0);
  float kx = __fmul_rn(nf, w0);
  F[idx] = __fsqrt_rn(__fadd_rn(__fmul_rn(ky, ky), __fmul_rn(kx, kx)));
}

// G[b,i,l] = sum_{j<128} x[b,i,j] * Cy[l, 128+j]
__global__ void gemm1_kernel(const float* __restrict__ x, const float* __restrict__ Cy,
                             float* __restrict__ G) {
  __shared__ float xs[128];
  int b = blockIdx.x >> 7;
  int i = blockIdx.x & 127;
  const float* xr = x + (b * 128 + i) * 128;
  if (threadIdx.x < 128) xs[threadIdx.x] = xr[threadIdx.x];
  __syncthreads();
  for (int l = threadIdx.x; l < 512; l += THREADS) {
    const float* crow = Cy + l * 512 + 128;
    float acc = 0.0f;
#pragma unroll 8
    for (int j = 0; j < 128; ++j) acc = fmaf(xs[j], crow[j], acc);
    G[(b * 128 + i) * 512 + l] = acc;
  }
}

// Mt[b,l,k] = Cy[k,0] * sum_{i<128} Cy[k,i] * G[b,i,l]   (transposed store: k contiguous)
__global__ void gemm2_kernel(const float* __restrict__ Cy, const float* __restrict__ G,
                             float* __restrict__ Mt) {
  __shared__ float as_[128];
  int b = blockIdx.x >> 9;
  int k = blockIdx.x & 511;
  if (threadIdx.x < 128) as_[threadIdx.x] = Cy[k * 512 + threadIdx.x];
  __syncthreads();
  float ak = as_[0];
  const float* Gb = G + b * 128 * 512;
  for (int l = threadIdx.x; l < 512; l += THREADS) {
    float acc = 0.0f;
#pragma unroll 8
    for (int i = 0; i < 128; ++i) acc = fmaf(as_[i], Gb[i * 512 + l], acc);
    Mt[(b * 512 + l) * 512 + k] = __fmul_rn(ak, acc);
  }
}

// Vt[j,b,t] = sum_k cos(F[j,k]*t) * Mt[b,j,k]   (F symmetric)
// Block = (j, t-half); F/Mt rows staged in LDS (broadcast reads); coalesced Vt store.
__global__ __launch_bounds__(256) void stageB_kernel(const float* __restrict__ F,
                                                     const float* __restrict__ Mt,
                                                     float* __restrict__ Vt) {
  __shared__ float fs[512], m0s[512], m1s[512];
  int j = blockIdx.x >> 1;
  int thalf = blockIdx.x & 1;
  int tid = threadIdx.x;
  const float* Fr = F + (j << 9);
  const float* M0 = Mt + (j << 9);
  const float* M1 = Mt + ((512 + j) << 9);
  fs[tid] = Fr[tid];        fs[tid + 256] = Fr[tid + 256];
  m0s[tid] = M0[tid];       m0s[tid + 256] = M0[tid + 256];
  m1s[tid] = M1[tid];       m1s[tid + 256] = M1[tid + 256];
  __syncthreads();
  int t = (thalf << 8) + tid;
  float tf = (float)t;
  float acc0 = 0.f, acc1 = 0.f;
#pragma unroll 8
  for (int k = 0; k < 512; ++k) {
    float ph = __cosf(__fmul_rn(fs[k], tf));  // arg bit-matches ref's f32 F*t
    acc0 = fmaf(ph, m0s[k], acc0);
    acc1 = fmaf(ph, m1s[k], acc1);
  }
  Vt[(j << 10) + t] = acc0;
  Vt[(j << 10) + 512 + t] = acc1;
}

// out[b,t,l] = (1/3) * sum_j Cy[j,l] * Vt[j,b,t]
// Block = (t-pair, l-half). One-time gather of 4 Vt columns into quad-packed LDS,
// then per-j: 1 coalesced Cy load + 1 broadcast ds_read_b128 + 4 fma.
__global__ __launch_bounds__(256) void stageC_kernel(const float* __restrict__ Cy,
                                                     const float* __restrict__ Vt,
                                                     float* __restrict__ out,
                                                     float* __restrict__ partial) {
  __shared__ float vq[2048];  // [j][4] = {b0t0, b1t0, b0t1, b1t1}
  int tpair = blockIdx.x >> 1;
  int lhalf = blockIdx.x & 1;
  int t0 = tpair << 1;
  int tid = threadIdx.x;
#pragma unroll
  for (int r = 0; r < 2; ++r) {
    int j = tid + (r << 8);
    const float* base = Vt + (j << 10);
    vq[(j << 2) + 0] = base[t0];
    vq[(j << 2) + 1] = base[512 + t0];
    vq[(j << 2) + 2] = base[t0 + 1];
    vq[(j << 2) + 3] = base[512 + t0 + 1];
  }
  __syncthreads();
  int l = (lhalf << 8) + tid;
  float a00 = 0.f, a01 = 0.f, a10 = 0.f, a11 = 0.f;
#pragma unroll 8
  for (int j = 0; j < 512; ++j) {
    float c = Cy[(j << 9) + l];
    float4 v = *(const float4*)&vq[j << 2];
    a00 = fmaf(c, v.x, a00);
    a01 = fmaf(c, v.y, a01);
    a10 = fmaf(c, v.z, a10);
    a11 = fmaf(c, v.w, a11);
  }
  float p00 = a00 / 3.0f, p01 = a01 / 3.0f, p10 = a10 / 3.0f, p11 = a11 / 3.0f;
  out[(t0 << 9) + l] = p00;
  out[((t0 + 1) << 9) + l] = p10;
  out[HALF_N + (t0 << 9) + l] = p01;
  out[HALF_N + ((t0 + 1) << 9) + l] = p11;
  float s0 = p00 + p10, q0 = fmaf(p00, p00, p10 * p10);
  float s1 = p01 + p11, q1 = fmaf(p01, p01, p11 * p11);
  for (int off = 32; off > 0; off >>= 1) {
    s0 += __shfl_down(s0, off);
    q0 += __shfl_down(q0, off);
    s1 += __shfl_down(s1, off);
    q1 += __shfl_down(q1, off);
  }
  __shared__ float red[4][4];
  int wave = tid >> 6;
  if ((tid & 63) == 0) {
    red[wave][0] = s0; red[wave][1] = q0; red[wave][2] = s1; red[wave][3] = q1;
  }
  __syncthreads();
  if (tid == 0) {
    float a0 = 0.f, a1 = 0.f, a2 = 0.f, a3 = 0.f;
    for (int wv = 0; wv < 4; ++wv) {
      a0 += red[wv][0]; a1 += red[wv][1]; a2 += red[wv][2]; a3 += red[wv][3];
    }
    partial[blockIdx.x * 4 + 0] = a0;
    partial[blockIdx.x * 4 + 1] = a1;
    partial[blockIdx.x * 4 + 2] = a2;
    partial[blockIdx.x * 4 + 3] = a3;
  }
}

// reduce 512 block-partials -> std per batch (population std, matches jnp.std)
__global__ __launch_bounds__(512) void stats_kernel(const float* __restrict__ partial,
                                                    float* __restrict__ stats) {
  float s0 = partial[threadIdx.x * 4 + 0];
  float q0 = partial[threadIdx.x * 4 + 1];
  float s1 = partial[threadIdx.x * 4 + 2];
  float q1 = partial[threadIdx.x * 4 + 3];
  for (int off = 32; off > 0; off >>= 1) {
    s0 += __shfl_down(s0, off);
    q0 += __shfl_down(q0, off);
    s1 += __shfl_down(s1, off);
    q1 += __shfl_down(q1, off);
  }
  __shared__ float red[8][4];
  int wave = threadIdx.x >> 6;
  if ((threadIdx.x & 63) == 0) {
    red[wave][0] = s0; red[wave][1] = q0; red[wave][2] = s1; red[wave][3] = q1;
  }
  __syncthreads();
  if (threadIdx.x == 0) {
    float S = 0.f, Q = 0.f, S2 = 0.f, Q2 = 0.f;
    for (int wv = 0; wv < 8; ++wv) {
      S += red[wv][0]; Q += red[wv][1]; S2 += red[wv][2]; Q2 += red[wv][3];
    }
    const float invN = 1.0f / 262144.0f;
    float m0 = S * invN, m1 = S2 * invN;
    stats[0] = __fsqrt_rn(fmaxf(Q * invN - m0 * m0, 0.0f));
    stats[1] = __fsqrt_rn(fmaxf(Q2 * invN - m1 * m1, 0.0f));
  }
}

// JAX threefry, partitionable: element i -> threefry2x32(key=(0,42), ctr=(0,i)), bits=o0^o1
__global__ void noise_kernel(float* __restrict__ out, const float* __restrict__ stats) {
  int i = blockIdx.x * THREADS + threadIdx.x;  // < 524288
  uint32_t x0 = 0u;
  uint32_t x1 = (uint32_t)i;
  const uint32_t k0 = 0u, k1 = 42u;
  const uint32_t k2 = k0 ^ k1 ^ 0x1BD11BDAu;
  x0 += k0; x1 += k1;
#define QR(r) x0 += x1; x1 = rotl32(x1, r); x1 ^= x0;
  QR(13) QR(15) QR(26) QR(6)
  x0 += k1; x1 += k2 + 1u;
  QR(17) QR(29) QR(16) QR(24)
  x0 += k2; x1 += k0 + 2u;
  QR(13) QR(15) QR(26) QR(6)
  x0 += k0; x1 += k1 + 3u;
  QR(17) QR(29) QR(16) QR(24)
  x0 += k1; x1 += k2 + 4u;
  QR(13) QR(15) QR(26) QR(6)
  x0 += k2; x1 += k0 + 5u;
#undef QR
  uint32_t bits = x0 ^ x1;
  const float lo = __uint_as_float(0xBF7FFFFFu);  // nextafter(-1,0)
  float f = __uint_as_float((bits >> 9) | 0x3F800000u) - 1.0f;
  float u = fmaxf(lo, __fadd_rn(__fmul_rn(f, 2.0f), lo));
  const float sqrt2 = 1.41421356237309515f;
  out[i] += stats[i >> 18] * (sqrt2 * erfinv_xla(u));
}

extern "C" void kernel_launch(void* const* d_in, const int* in_sizes, int n_in,
                              void* d_out, int out_size, void* d_ws, size_t ws_size,
                              hipStream_t stream) {
  const float* x = (const float*)d_in[0];
  float* ws = (float*)d_ws;
  float* Cy      = ws;
  float* G       = ws + 262144;
  float* partial = ws + 262144;  // overlays G (G dead after gemm2)
  float* stats   = ws + 264192;
  float* Mt      = ws + 393216;
  float* F       = ws + 917504;
  float* Vt      = ws + 1179648;
  float* out = (float*)d_out;

  init_kernel<<<1024, THREADS, 0, stream>>>(Cy, F);
  gemm1_kernel<<<256, THREADS, 0, stream>>>(x, Cy, G);
  gemm2_kernel<<<1024, THREADS, 0, stream>>>(Cy, G, Mt);
  stageB_kernel<<<1024, THREADS, 0, stream>>>(F, Mt, Vt);
  stageC_kernel<<<512, THREADS, 0, stream>>>(Cy, Vt, out, partial);
  stats_kernel<<<1, 512, 0, stream>>>(partial, stats);
  noise_kernel<<<2048, THREADS, 0, stream>>>(out, stats);
}

// Round 5
// 147.939 us; speedup vs baseline: 1.2794x; 1.0409x over previous
//
#include <hip/hip_runtime.h>
#include <stdint.h>
#include <math.h>

// PhysicsForwardModel: B=2, Nz=Nx=128, Ly=Lx=512.
// out[b,t,l] = (1/3) * sum_j Cy[j,l] * sum_k cos(F[k,j]*t) * a[k] * (Cy[:, :128] x[b] Cy[:,128:256]^T)[k,j]
//              + std_b * N(0,1)  (JAX threefry key=42, partitionable counters, XLA erfinv)

#define THREADS 256
#define HALF_N 262144  // 512*512 = per-batch element count

// ---------------- ws layout (float offsets) ----------------
// Cy      [0       .. 262144)   512x512 DCT-II matrix
// G       [262144  .. 393216)   B x 128 x 512 (dead after gemm2)
// partial [262144  .. 264192)   512 blocks x {s0,q0,s1,q1}   (overlays dead G)
// Mt      [393216  .. 917504)   B x 512(l) x 512(k) : transposed M, k contiguous
// F       [917504  .. 1179648)  512x512 radial frequency (symmetric)
// Vt      [1179648 .. 1703936)  [j][b][t] : 512 x 2 x 512, t contiguous

__device__ __forceinline__ uint32_t rotl32(uint32_t v, int r) {
  return (v << r) | (v >> (32 - r));
}

// XLA ErfInv32 (Giles) -- matches reference's lax.erf_inv
__device__ __forceinline__ float erfinv_xla(float x) {
  float w = -log1pf(__fmul_rn(-x, x));
  float p;
  if (w < 5.0f) {
    w = w - 2.5f;
    p = 2.81022636e-08f;
    p = fmaf(p, w, 3.43273939e-07f);
    p = fmaf(p, w, -3.5233877e-06f);
    p = fmaf(p, w, -4.39150654e-06f);
    p = fmaf(p, w, 0.00021858087f);
    p = fmaf(p, w, -0.00125372503f);
    p = fmaf(p, w, -0.00417768164f);
    p = fmaf(p, w, 0.246640727f);
    p = fmaf(p, w, 1.50140941f);
  } else {
    w = __fsqrt_rn(w) - 3.0f;
    p = -0.000200214257f;
    p = fmaf(p, w, 0.000100950558f);
    p = fmaf(p, w, 0.00134934322f);
    p = fmaf(p, w, -0.00367342844f);
    p = fmaf(p, w, 0.00573950773f);
    p = fmaf(p, w, -0.0076224613f);
    p = fmaf(p, w, 0.00943887047f);
    p = fmaf(p, w, 1.00167406f);
    p = fmaf(p, w, 2.83297682f);
  }
  return p * x;
}

// Cy[k,n] = s[k]*2*cos(pi*(2n+1)*k/1024);  F[k,j] = sqrt(ky[k]^2+kx[j]^2)
__global__ void init_kernel(float* __restrict__ Cy, float* __restrict__ F) {
  int idx = blockIdx.x * THREADS + threadIdx.x;  // < 262144
  int k = idx >> 9;
  int n = idx & 511;
  float nf = (float)n, kf = (float)k;
  const float pi_f = 3.14159274101257324f;
  float t1 = __fmul_rn(pi_f, __fadd_rn(__fmul_rn(2.0f, nf), 1.0f));
  float t2 = __fmul_rn(t1, kf);
  float arg = t2 * (1.0f / 1024.0f);
  float s = (k == 0) ? (1.0f / __fsqrt_rn(2048.0f)) : 0.03125f;
  Cy[idx] = __fmul_rn(s, __fmul_rn(2.0f, cosf(arg)));

  const float w0 = 3.14159274101257324f / 512.0f;  // exact: pi_f * 2^-9
  float ky = __fmul_rn(kf, w0);
  float kx = __fmul_rn(nf, w0);
  F[idx] = __fsqrt_rn(__fadd_rn(__fmul_rn(ky, ky), __fmul_rn(kx, kx)));
}

// G[b,i,l] = sum_{j<128} x[b,i,j] * Cy[l, 128+j]
__global__ void gemm1_kernel(const float* __restrict__ x, const float* __restrict__ Cy,
                             float* __restrict__ G) {
  __shared__ float xs[128];
  int b = blockIdx.x >> 7;
  int i = blockIdx.x & 127;
  const float* xr = x + (b * 128 + i) * 128;
  if (threadIdx.x < 128) xs[threadIdx.x] = xr[threadIdx.x];
  __syncthreads();
  for (int l = threadIdx.x; l < 512; l += THREADS) {
    const float* crow = Cy + l * 512 + 128;
    float acc = 0.0f;
#pragma unroll 8
    for (int j = 0; j < 128; ++j) acc = fmaf(xs[j], crow[j], acc);
    G[(b * 128 + i) * 512 + l] = acc;
  }
}

// Mt[b,l,{k0,k0+1}] = Cy[k,0] * sum_i Cy[k,i] * G[b,i,l]; k-pair per block halves G re-reads
__global__ __launch_bounds__(256) void gemm2_kernel(const float* __restrict__ Cy,
                                                    const float* __restrict__ G,
                                                    float* __restrict__ Mt) {
  __shared__ float as_[2][128];
  int b = blockIdx.x >> 8;
  int k0 = (blockIdx.x & 255) << 1;
  int tid = threadIdx.x;
  {
    int w = tid >> 7, i = tid & 127;
    as_[w][i] = Cy[(k0 + w) * 512 + i];
  }
  __syncthreads();
  float a0 = as_[0][0], a1 = as_[1][0];
  const float* Gb = G + b * 65536;
#pragma unroll
  for (int r = 0; r < 2; ++r) {
    int l = tid + (r << 8);
    float acc0 = 0.f, acc1 = 0.f;
#pragma unroll 8
    for (int i = 0; i < 128; ++i) {
      float g = Gb[i * 512 + l];
      acc0 = fmaf(as_[0][i], g, acc0);
      acc1 = fmaf(as_[1][i], g, acc1);
    }
    *(float2*)&Mt[(b * 512 + l) * 512 + k0] =
        make_float2(__fmul_rn(a0, acc0), __fmul_rn(a1, acc1));
  }
}

// Vt[j,b,t] = sum_k cos(F[j,k]*t) * Mt[b,j,k]   (F symmetric)
// Block = (j, t-quarter); F + float2-interleaved M staged in LDS.
__global__ __launch_bounds__(128) void stageB_kernel(const float* __restrict__ F,
                                                     const float* __restrict__ Mt,
                                                     float* __restrict__ Vt) {
  __shared__ float fs[512];
  __shared__ float2 ms[512];
  int j = blockIdx.x >> 2;
  int tq = blockIdx.x & 3;
  int tid = threadIdx.x;
  const float* Fr = F + (j << 9);
  const float* M0 = Mt + (j << 9);
  const float* M1 = Mt + ((512 + j) << 9);
#pragma unroll
  for (int r = 0; r < 4; ++r) {
    int k = tid + (r << 7);
    fs[k] = Fr[k];
    ms[k] = make_float2(M0[k], M1[k]);
  }
  __syncthreads();
  int t = (tq << 7) + tid;
  float tf = (float)t;
  float acc0 = 0.f, acc1 = 0.f;
#pragma unroll 8
  for (int k = 0; k < 512; ++k) {
    float ph = __cosf(__fmul_rn(fs[k], tf));  // arg bit-matches ref's f32 F*t
    float2 m = ms[k];
    acc0 = fmaf(ph, m.x, acc0);
    acc1 = fmaf(ph, m.y, acc1);
  }
  Vt[(j << 10) + t] = acc0;
  Vt[(j << 10) + 512 + t] = acc1;
}

// out[b,t,l] = (1/3) * sum_j Cy[j,l] * Vt[j,b,t]
// Block = (t-pair, l-half). Gather 4 Vt columns into quad-packed LDS once,
// then per-j: 1 coalesced Cy load + 1 broadcast ds_read_b128 + 4 fma.
__global__ __launch_bounds__(256) void stageC_kernel(const float* __restrict__ Cy,
                                                     const float* __restrict__ Vt,
                                                     float* __restrict__ out,
                                                     float* __restrict__ partial) {
  __shared__ float vq[2048];  // [j][4] = {b0t0, b1t0, b0t1, b1t1}
  int tpair = blockIdx.x >> 1;
  int lhalf = blockIdx.x & 1;
  int t0 = tpair << 1;
  int tid = threadIdx.x;
#pragma unroll
  for (int r = 0; r < 2; ++r) {
    int j = tid + (r << 8);
    const float* base = Vt + (j << 10);
    vq[(j << 2) + 0] = base[t0];
    vq[(j << 2) + 1] = base[512 + t0];
    vq[(j << 2) + 2] = base[t0 + 1];
    vq[(j << 2) + 3] = base[512 + t0 + 1];
  }
  __syncthreads();
  int l = (lhalf << 8) + tid;
  float a00 = 0.f, a01 = 0.f, a10 = 0.f, a11 = 0.f;
#pragma unroll 8
  for (int j = 0; j < 512; ++j) {
    float c = Cy[(j << 9) + l];
    float4 v = *(const float4*)&vq[j << 2];
    a00 = fmaf(c, v.x, a00);
    a01 = fmaf(c, v.y, a01);
    a10 = fmaf(c, v.z, a10);
    a11 = fmaf(c, v.w, a11);
  }
  float p00 = a00 / 3.0f, p01 = a01 / 3.0f, p10 = a10 / 3.0f, p11 = a11 / 3.0f;
  out[(t0 << 9) + l] = p00;
  out[((t0 + 1) << 9) + l] = p10;
  out[HALF_N + (t0 << 9) + l] = p01;
  out[HALF_N + ((t0 + 1) << 9) + l] = p11;
  float s0 = p00 + p10, q0 = fmaf(p00, p00, p10 * p10);
  float s1 = p01 + p11, q1 = fmaf(p01, p01, p11 * p11);
  for (int off = 32; off > 0; off >>= 1) {
    s0 += __shfl_down(s0, off);
    q0 += __shfl_down(q0, off);
    s1 += __shfl_down(s1, off);
    q1 += __shfl_down(q1, off);
  }
  __shared__ float red[4][4];
  int wave = tid >> 6;
  if ((tid & 63) == 0) {
    red[wave][0] = s0; red[wave][1] = q0; red[wave][2] = s1; red[wave][3] = q1;
  }
  __syncthreads();
  if (tid == 0) {
    float a0 = 0.f, a1 = 0.f, a2 = 0.f, a3 = 0.f;
    for (int wv = 0; wv < 4; ++wv) {
      a0 += red[wv][0]; a1 += red[wv][1]; a2 += red[wv][2]; a3 += red[wv][3];
    }
    partial[blockIdx.x * 4 + 0] = a0;
    partial[blockIdx.x * 4 + 1] = a1;
    partial[blockIdx.x * 4 + 2] = a2;
    partial[blockIdx.x * 4 + 3] = a3;
  }
}

// Fused stats + noise: every block redundantly reduces the 512x4 partials to
// (std0,std1), then adds JAX-threefry normal noise to its 256 output elements.
// element i -> threefry2x32(key=(0,42), ctr=(0,i)), bits = o0^o1
__global__ __launch_bounds__(256) void noise_kernel(float* __restrict__ out,
                                                    const float* __restrict__ partial) {
  int tid = threadIdx.x;
  const float4* pq = (const float4*)partial;  // 512 quads {s0,q0,s1,q1}
  float4 pa = pq[tid];
  float4 pb = pq[tid + 256];
  float s0 = pa.x + pb.x, q0 = pa.y + pb.y, s1 = pa.z + pb.z, q1 = pa.w + pb.w;
  for (int off = 32; off > 0; off >>= 1) {
    s0 += __shfl_down(s0, off);
    q0 += __shfl_down(q0, off);
    s1 += __shfl_down(s1, off);
    q1 += __shfl_down(q1, off);
  }
  __shared__ float red[4][4];
  int wave = tid >> 6;
  if ((tid & 63) == 0) {
    red[wave][0] = s0; red[wave][1] = q0; red[wave][2] = s1; red[wave][3] = q1;
  }
  __syncthreads();
  float S = red[0][0] + red[1][0] + red[2][0] + red[3][0];
  float Q = red[0][1] + red[1][1] + red[2][1] + red[3][1];
  float S2 = red[0][2] + red[1][2] + red[2][2] + red[3][2];
  float Q2 = red[0][3] + red[1][3] + red[2][3] + red[3][3];
  const float invN = 1.0f / 262144.0f;
  float m0 = S * invN, m1 = S2 * invN;
  float std0 = __fsqrt_rn(fmaxf(Q * invN - m0 * m0, 0.0f));
  float std1 = __fsqrt_rn(fmaxf(Q2 * invN - m1 * m1, 0.0f));

  int i = blockIdx.x * 256 + tid;  // < 524288
  uint32_t x0 = 0u;
  uint32_t x1 = (uint32_t)i;
  const uint32_t k0 = 0u, k1 = 42u;
  const uint32_t k2 = k0 ^ k1 ^ 0x1BD11BDAu;
  x0 += k0; x1 += k1;
#define QR(r) x0 += x1; x1 = rotl32(x1, r); x1 ^= x0;
  QR(13) QR(15) QR(26) QR(6)
  x0 += k1; x1 += k2 + 1u;
  QR(17) QR(29) QR(16) QR(24)
  x0 += k2; x1 += k0 + 2u;
  QR(13) QR(15) QR(26) QR(6)
  x0 += k0; x1 += k1 + 3u;
  QR(17) QR(29) QR(16) QR(24)
  x0 += k1; x1 += k2 + 4u;
  QR(13) QR(15) QR(26) QR(6)
  x0 += k2; x1 += k0 + 5u;
#undef QR
  uint32_t bits = x0 ^ x1;
  const float lo = __uint_as_float(0xBF7FFFFFu);  // nextafter(-1,0)
  float f = __uint_as_float((bits >> 9) | 0x3F800000u) - 1.0f;
  float u = fmaxf(lo, __fadd_rn(__fmul_rn(f, 2.0f), lo));
  const float sqrt2 = 1.41421356237309515f;
  out[i] += (i < HALF_N ? std0 : std1) * (sqrt2 * erfinv_xla(u));
}

extern "C" void kernel_launch(void* const* d_in, const int* in_sizes, int n_in,
                              void* d_out, int out_size, void* d_ws, size_t ws_size,
                              hipStream_t stream) {
  const float* x = (const float*)d_in[0];
  float* ws = (float*)d_ws;
  float* Cy      = ws;
  float* G       = ws + 262144;
  float* partial = ws + 262144;  // overlays G (G dead after gemm2)
  float* Mt      = ws + 393216;
  float* F       = ws + 917504;
  float* Vt      = ws + 1179648;
  float* out = (float*)d_out;

  init_kernel<<<1024, THREADS, 0, stream>>>(Cy, F);
  gemm1_kernel<<<256, THREADS, 0, stream>>>(x, Cy, G);
  gemm2_kernel<<<512, 256, 0, stream>>>(Cy, G, Mt);
  stageB_kernel<<<2048, 128, 0, stream>>>(F, Mt, Vt);
  stageC_kernel<<<512, THREADS, 0, stream>>>(Cy, Vt, out, partial);
  noise_kernel<<<2048, 256, 0, stream>>>(out, partial);
}

// Round 7
// 133.751 us; speedup vs baseline: 1.4151x; 1.1061x over previous
//
#include <hip/hip_runtime.h>
#include <stdint.h>
#include <math.h>

// PhysicsForwardModel: B=2, Nz=Nx=128, Ly=Lx=512.
// out[b,t,l] = (1/3) * sum_j Cy[j,l] * sum_k cos(F[k,j]*t) * a[k] * (Cy[:,:128] x[b] Cy[:,128:256]^T)[k,j]
//              + std_b * N(0,1)  (JAX threefry key=42, partitionable counters, XLA erfinv)
// Cy/F are never materialized: each consumer recomputes its rows/cols via __cosf
// (pow2 scale muls are exact, so op-order matches the reference's f32 sequence).

#define HALF_N 262144  // 512*512 per-batch elements
#define PI_F 3.14159274101257324f

// ---------------- ws layout (float offsets) ----------------
// Gt      [0      .. 131072)  [b][l][i] : gemm1 output, transposed (i contiguous)
// Vt      [131072 .. 655360)  [j][b][t] : t contiguous
// partial [655360 .. 657408)  512 blocks x {s0,q0,s1,q1}

__device__ __forceinline__ uint32_t rotl32(uint32_t v, int r) {
  return (v << r) | (v >> (32 - r));
}

// XLA ErfInv32 (Giles) -- matches reference's lax.erf_inv
__device__ __forceinline__ float erfinv_xla(float x) {
  float w = -log1pf(__fmul_rn(-x, x));
  float p;
  if (w < 5.0f) {
    w = w - 2.5f;
    p = 2.81022636e-08f;
    p = fmaf(p, w, 3.43273939e-07f);
    p = fmaf(p, w, -3.5233877e-06f);
    p = fmaf(p, w, -4.39150654e-06f);
    p = fmaf(p, w, 0.00021858087f);
    p = fmaf(p, w, -0.00125372503f);
    p = fmaf(p, w, -0.00417768164f);
    p = fmaf(p, w, 0.246640727f);
    p = fmaf(p, w, 1.50140941f);
  } else {
    w = __fsqrt_rn(w) - 3.0f;
    p = -0.000200214257f;
    p = fmaf(p, w, 0.000100950558f);
    p = fmaf(p, w, 0.00134934322f);
    p = fmaf(p, w, -0.00367342844f);
    p = fmaf(p, w, 0.00573950773f);
    p = fmaf(p, w, -0.0076224613f);
    p = fmaf(p, w, 0.00943887047f);
    p = fmaf(p, w, 1.00167406f);
    p = fmaf(p, w, 2.83297682f);
  }
  return p * x;
}

// Gt[b,l,i] = sum_{jj<128} x[b,i,jj] * Cy[l,128+jj]; block = l, Cy row slice on the fly
__global__ __launch_bounds__(256) void gemm1_kernel(const float* __restrict__ x,
                                                    float* __restrict__ Gt) {
  __shared__ float cyl[128];
  int l = blockIdx.x;
  int tid = threadIdx.x;
  float lf = (float)l;
  float sc = (l == 0) ? (1.0f / __fsqrt_rn(2048.0f)) : 0.03125f;
  if (tid < 128) {
    int n = 128 + tid;
    float t1 = __fmul_rn(PI_F, (float)(2 * n + 1));
    float arg = __fmul_rn(t1, lf) * (1.0f / 1024.0f);
    cyl[tid] = __fmul_rn(sc, __fmul_rn(2.0f, __cosf(arg)));
  }
  __syncthreads();
  int b = tid >> 7, i = tid & 127;
  const float* xr = x + (b * 128 + i) * 128;
  float acc = 0.0f;
#pragma unroll 8
  for (int jj = 0; jj < 128; ++jj) acc = fmaf(xr[jj], cyl[jj], acc);
  Gt[(b * 512 + l) * 128 + i] = acc;
}

// fusedB (gemm2+stageB), block = j, 512 threads:
//   phase B (lane=k): Mcol[b,k] = Cy[k,0] * sum_i Cy[k,i]*Gt[b,j,i]; F[k,j] -> LDS
//   phase C (lane=t): Vt[j,b,t] = sum_k cos(F[k]*t) * Mcol[b,k]
__global__ __launch_bounds__(512) void stageB_kernel(const float* __restrict__ Gt,
                                                     float* __restrict__ Vt) {
  __shared__ float us[256];
  __shared__ float fs[512];
  __shared__ float2 ms[512];
  int j = blockIdx.x;
  int tid = threadIdx.x;
  if (tid < 256) {
    int b = tid >> 7, i = tid & 127;
    us[tid] = Gt[(b * 512 + j) * 128 + i];
  }
  __syncthreads();
  {
    float kf = (float)tid;
    float sc = (tid == 0) ? (1.0f / __fsqrt_rn(2048.0f)) : 0.03125f;
    // i = 0 peeled: a[k] = Cy[k,0]
    float arg0 = __fmul_rn(__fmul_rn(PI_F, 1.0f), kf) * (1.0f / 1024.0f);
    float a = __fmul_rn(sc, __fmul_rn(2.0f, __cosf(arg0)));
    float acc0 = __fmul_rn(a, us[0]);
    float acc1 = __fmul_rn(a, us[128]);
#pragma unroll 16
    for (int i = 1; i < 128; ++i) {
      float t1 = __fmul_rn(PI_F, (float)(2 * i + 1));
      float arg = __fmul_rn(t1, kf) * (1.0f / 1024.0f);
      float cy = __fmul_rn(sc, __fmul_rn(2.0f, __cosf(arg)));
      acc0 = fmaf(cy, us[i], acc0);
      acc1 = fmaf(cy, us[128 + i], acc1);
    }
    const float w0 = PI_F / 512.0f;  // exact pow2 scale of pi_f
    float ky = __fmul_rn(kf, w0);
    float kx = __fmul_rn((float)j, w0);
    fs[tid] = __fsqrt_rn(__fadd_rn(__fmul_rn(ky, ky), __fmul_rn(kx, kx)));
    ms[tid] = make_float2(__fmul_rn(a, acc0), __fmul_rn(a, acc1));
  }
  __syncthreads();
  float tf = (float)tid;
  float acc0 = 0.f, acc1 = 0.f;
#pragma unroll 8
  for (int k = 0; k < 512; ++k) {
    float ph = __cosf(__fmul_rn(fs[k], tf));  // arg bit-matches ref's f32 F*t
    float2 m = ms[k];
    acc0 = fmaf(ph, m.x, acc0);
    acc1 = fmaf(ph, m.y, acc1);
  }
  Vt[(j << 10) + tid] = acc0;
  Vt[(j << 10) + 512 + tid] = acc1;
}

// fusedC: out[b,t,l] = (1/3) * sum_j Cy[j,l] * Vt[j,b,t]; Cy[j,l] on the fly.
// Block = (t-pair, l-half); gather 4 Vt columns into quad-packed LDS once.
__global__ __launch_bounds__(256) void stageC_kernel(const float* __restrict__ Vt,
                                                     float* __restrict__ out,
                                                     float* __restrict__ partial) {
  __shared__ float vq[2048];  // [j][4] = {b0t0, b1t0, b0t1, b1t1}
  int tpair = blockIdx.x >> 1;
  int lhalf = blockIdx.x & 1;
  int t0 = tpair << 1;
  int tid = threadIdx.x;
#pragma unroll
  for (int r = 0; r < 2; ++r) {
    int j = tid + (r << 8);
    const float* base = Vt + (j << 10);
    vq[(j << 2) + 0] = base[t0];
    vq[(j << 2) + 1] = base[512 + t0];
    vq[(j << 2) + 2] = base[t0 + 1];
    vq[(j << 2) + 3] = base[512 + t0 + 1];
  }
  __syncthreads();
  int l = (lhalf << 8) + tid;
  float t1 = __fmul_rn(PI_F, (float)(2 * l + 1));  // per-lane row factor
  // j = 0 peeled: Cy[0,l] = s0 * 2 * cos(0)
  float cy0 = __fmul_rn(1.0f / __fsqrt_rn(2048.0f), 2.0f);
  float4 v0 = *(const float4*)&vq[0];
  float a00 = __fmul_rn(cy0, v0.x);
  float a01 = __fmul_rn(cy0, v0.y);
  float a10 = __fmul_rn(cy0, v0.z);
  float a11 = __fmul_rn(cy0, v0.w);
#pragma unroll 8
  for (int j = 1; j < 512; ++j) {
    float arg = __fmul_rn(t1, (float)j) * (1.0f / 1024.0f);
    float c = __fmul_rn(0.0625f, __cosf(arg));  // = 0.03125*(2*cos), both muls exact
    float4 v = *(const float4*)&vq[j << 2];
    a00 = fmaf(c, v.x, a00);
    a01 = fmaf(c, v.y, a01);
    a10 = fmaf(c, v.z, a10);
    a11 = fmaf(c, v.w, a11);
  }
  float p00 = a00 / 3.0f, p01 = a01 / 3.0f, p10 = a10 / 3.0f, p11 = a11 / 3.0f;
  out[(t0 << 9) + l] = p00;
  out[((t0 + 1) << 9) + l] = p10;
  out[HALF_N + (t0 << 9) + l] = p01;
  out[HALF_N + ((t0 + 1) << 9) + l] = p11;
  float s0 = p00 + p10, q0 = fmaf(p00, p00, p10 * p10);
  float s1 = p01 + p11, q1 = fmaf(p01, p01, p11 * p11);
  for (int off = 32; off > 0; off >>= 1) {
    s0 += __shfl_down(s0, off);
    q0 += __shfl_down(q0, off);
    s1 += __shfl_down(s1, off);
    q1 += __shfl_down(q1, off);
  }
  __shared__ float red[4][4];
  int wave = tid >> 6;
  if ((tid & 63) == 0) {
    red[wave][0] = s0; red[wave][1] = q0; red[wave][2] = s1; red[wave][3] = q1;
  }
  __syncthreads();
  if (tid == 0) {
    float a0 = 0.f, a1 = 0.f, a2 = 0.f, a3 = 0.f;
    for (int wv = 0; wv < 4; ++wv) {
      a0 += red[wv][0]; a1 += red[wv][1]; a2 += red[wv][2]; a3 += red[wv][3];
    }
    partial[blockIdx.x * 4 + 0] = a0;
    partial[blockIdx.x * 4 + 1] = a1;
    partial[blockIdx.x * 4 + 2] = a2;
    partial[blockIdx.x * 4 + 3] = a3;
  }
}

// Fused stats + noise: every block redundantly reduces the 512x4 partials to
// (std0,std1), then adds JAX-threefry normal noise to its 256 output elements.
// element i -> threefry2x32(key=(0,42), ctr=(0,i)), bits = o0^o1
__global__ __launch_bounds__(256) void noise_kernel(float* __restrict__ out,
                                                    const float* __restrict__ partial) {
  int tid = threadIdx.x;
  const float4* pq = (const float4*)partial;  // 512 quads {s0,q0,s1,q1}
  float4 pa = pq[tid];
  float4 pb = pq[tid + 256];
  float s0 = pa.x + pb.x, q0 = pa.y + pb.y, s1 = pa.z + pb.z, q1 = pa.w + pb.w;
  for (int off = 32; off > 0; off >>= 1) {
    s0 += __shfl_down(s0, off);
    q0 += __shfl_down(q0, off);
    s1 += __shfl_down(s1, off);
    q1 += __shfl_down(q1, off);
  }
  __shared__ float red[4][4];
  int wave = tid >> 6;
  if ((tid & 63) == 0) {
    red[wave][0] = s0; red[wave][1] = q0; red[wave][2] = s1; red[wave][3] = q1;
  }
  __syncthreads();
  float S = red[0][0] + red[1][0] + red[2][0] + red[3][0];
  float Q = red[0][1] + red[1][1] + red[2][1] + red[3][1];
  float S2 = red[0][2] + red[1][2] + red[2][2] + red[3][2];
  float Q2 = red[0][3] + red[1][3] + red[2][3] + red[3][3];
  const float invN = 1.0f / 262144.0f;
  float m0 = S * invN, m1 = S2 * invN;
  float std0 = __fsqrt_rn(fmaxf(Q * invN - m0 * m0, 0.0f));
  float std1 = __fsqrt_rn(fmaxf(Q2 * invN - m1 * m1, 0.0f));

  int i = blockIdx.x * 256 + tid;  // < 524288
  uint32_t x0 = 0u;
  uint32_t x1 = (uint32_t)i;
  const uint32_t k0 = 0u, k1 = 42u;
  const uint32_t k2 = k0 ^ k1 ^ 0x1BD11BDAu;
  x0 += k0; x1 += k1;
#define QR(r) x0 += x1; x1 = rotl32(x1, r); x1 ^= x0;
  QR(13) QR(15) QR(26) QR(6)
  x0 += k1; x1 += k2 + 1u;
  QR(17) QR(29) QR(16) QR(24)
  x0 += k2; x1 += k0 + 2u;
  QR(13) QR(15) QR(26) QR(6)
  x0 += k0; x1 += k1 + 3u;
  QR(17) QR(29) QR(16) QR(24)
  x0 += k1; x1 += k2 + 4u;
  QR(13) QR(15) QR(26) QR(6)
  x0 += k2; x1 += k0 + 5u;
#undef QR
  uint32_t bits = x0 ^ x1;
  const float lo = __uint_as_float(0xBF7FFFFFu);  // nextafter(-1,0)
  float f = __uint_as_float((bits >> 9) | 0x3F800000u) - 1.0f;
  float u = fmaxf(lo, __fadd_rn(__fmul_rn(f, 2.0f), lo));
  const float sqrt2 = 1.41421356237309515f;
  out[i] += (i < HALF_N ? std0 : std1) * (sqrt2 * erfinv_xla(u));
}

extern "C" void kernel_launch(void* const* d_in, const int* in_sizes, int n_in,
                              void* d_out, int out_size, void* d_ws, size_t ws_size,
                              hipStream_t stream) {
  const float* x = (const float*)d_in[0];
  float* ws = (float*)d_ws;
  float* Gt      = ws;
  float* Vt      = ws + 131072;
  float* partial = ws + 655360;
  float* out = (float*)d_out;

  gemm1_kernel<<<512, 256, 0, stream>>>(x, Gt);
  stageB_kernel<<<512, 512, 0, stream>>>(Gt, Vt);
  stageC_kernel<<<512, 256, 0, stream>>>(Vt, out, partial);
  noise_kernel<<<2048, 256, 0, stream>>>(out, partial);
}

// Round 8
// 131.841 us; speedup vs baseline: 1.4356x; 1.0145x over previous
//
#include <hip/hip_runtime.h>
#include <stdint.h>
#include <math.h>

// PhysicsForwardModel: B=2, Nz=Nx=128, Ly=Lx=512.
// out[b,t,l] = (1/3) * sum_j Cy[j,l] * sum_k cos(F[k,j]*t) * a[k] * (Cy[:,:128] x[b] Cy[:,128:256]^T)[k,j]
//              + std_b * N(0,1)  (JAX threefry key=42, partitionable counters, XLA erfinv)
// Cy/F are never materialized: each consumer recomputes its rows/cols via __cosf
// (pow2 scale muls are exact, so op-order matches the reference's f32 sequence).
// 3 kernels: fusedB (gemm1+gemm2+phase-scan), stageC (inverse DCT + std partials),
// noise (redundant stats reduce + threefry normal).

#define HALF_N 262144  // 512*512 per-batch elements
#define PI_F 3.14159274101257324f

// ---------------- ws layout (float offsets) ----------------
// Vt      [0      .. 524288)  [j][b][t] : t contiguous
// partial [524288 .. 526336)  512 blocks x {s0,q0,s1,q1}

__device__ __forceinline__ uint32_t rotl32(uint32_t v, int r) {
  return (v << r) | (v >> (32 - r));
}

// XLA ErfInv32 (Giles) -- matches reference's lax.erf_inv
__device__ __forceinline__ float erfinv_xla(float x) {
  float w = -log1pf(__fmul_rn(-x, x));
  float p;
  if (w < 5.0f) {
    w = w - 2.5f;
    p = 2.81022636e-08f;
    p = fmaf(p, w, 3.43273939e-07f);
    p = fmaf(p, w, -3.5233877e-06f);
    p = fmaf(p, w, -4.39150654e-06f);
    p = fmaf(p, w, 0.00021858087f);
    p = fmaf(p, w, -0.00125372503f);
    p = fmaf(p, w, -0.00417768164f);
    p = fmaf(p, w, 0.246640727f);
    p = fmaf(p, w, 1.50140941f);
  } else {
    w = __fsqrt_rn(w) - 3.0f;
    p = -0.000200214257f;
    p = fmaf(p, w, 0.000100950558f);
    p = fmaf(p, w, 0.00134934322f);
    p = fmaf(p, w, -0.00367342844f);
    p = fmaf(p, w, 0.00573950773f);
    p = fmaf(p, w, -0.0076224613f);
    p = fmaf(p, w, 0.00943887047f);
    p = fmaf(p, w, 1.00167406f);
    p = fmaf(p, w, 2.83297682f);
  }
  return p * x;
}

// fusedB, block = j (grid 512, 512 threads):
//   phase A  (tid<128): cyl[jj] = Cy[j,128+jj]
//   phase A2 (tid<256): us[b*128+i] = sum_jj x[b,i,jj]*cyl[jj]      (= G[b,i,j])
//   phase B  (lane=k):  Mcol[b,k] = Cy[k,0]*sum_i Cy[k,i]*us[b,i]; F[k,j] -> LDS
//   phase C  (lane=t):  Vt[j,b,t] = sum_k cos(F[k]*t) * Mcol[b,k]
__global__ __launch_bounds__(512) void stageB_kernel(const float* __restrict__ x,
                                                     float* __restrict__ Vt) {
  __shared__ float cyl[128];
  __shared__ float us[256];
  __shared__ float fs[512];
  __shared__ float2 ms[512];
  int j = blockIdx.x;
  int tid = threadIdx.x;
  float jf = (float)j;
  if (tid < 128) {
    float scj = (j == 0) ? (1.0f / __fsqrt_rn(2048.0f)) : 0.03125f;
    int n = 128 + tid;
    float t1 = __fmul_rn(PI_F, (float)(2 * n + 1));
    float arg = __fmul_rn(t1, jf) * (1.0f / 1024.0f);
    cyl[tid] = __fmul_rn(scj, __fmul_rn(2.0f, __cosf(arg)));
  }
  __syncthreads();
  if (tid < 256) {
    int b = tid >> 7, i = tid & 127;
    const float* xr = x + (b * 128 + i) * 128;
    float acc = 0.0f;
#pragma unroll 8
    for (int jj = 0; jj < 128; ++jj) acc = fmaf(xr[jj], cyl[jj], acc);
    us[tid] = acc;
  }
  __syncthreads();
  {
    float kf = (float)tid;
    float sc = (tid == 0) ? (1.0f / __fsqrt_rn(2048.0f)) : 0.03125f;
    // i = 0 peeled: a[k] = Cy[k,0]
    float arg0 = __fmul_rn(__fmul_rn(PI_F, 1.0f), kf) * (1.0f / 1024.0f);
    float a = __fmul_rn(sc, __fmul_rn(2.0f, __cosf(arg0)));
    float acc0 = __fmul_rn(a, us[0]);
    float acc1 = __fmul_rn(a, us[128]);
#pragma unroll 16
    for (int i = 1; i < 128; ++i) {
      float t1 = __fmul_rn(PI_F, (float)(2 * i + 1));
      float arg = __fmul_rn(t1, kf) * (1.0f / 1024.0f);
      float cy = __fmul_rn(sc, __fmul_rn(2.0f, __cosf(arg)));
      acc0 = fmaf(cy, us[i], acc0);
      acc1 = fmaf(cy, us[128 + i], acc1);
    }
    const float w0 = PI_F / 512.0f;  // exact pow2 scale of pi_f
    float ky = __fmul_rn(kf, w0);
    float kx = __fmul_rn(jf, w0);
    fs[tid] = __fsqrt_rn(__fadd_rn(__fmul_rn(ky, ky), __fmul_rn(kx, kx)));
    ms[tid] = make_float2(__fmul_rn(a, acc0), __fmul_rn(a, acc1));
  }
  __syncthreads();
  float tf = (float)tid;
  float acc0 = 0.f, acc1 = 0.f;
#pragma unroll 8
  for (int k = 0; k < 512; ++k) {
    float ph = __cosf(__fmul_rn(fs[k], tf));  // arg bit-matches ref's f32 F*t
    float2 m = ms[k];
    acc0 = fmaf(ph, m.x, acc0);
    acc1 = fmaf(ph, m.y, acc1);
  }
  Vt[(j << 10) + tid] = acc0;
  Vt[(j << 10) + 512 + tid] = acc1;
}

// stageC: out[b,t,l] = (1/3) * sum_j Cy[j,l] * Vt[j,b,t]; Cy[j,l] on the fly.
// Block = (t-pair, l-half); gather 4 Vt columns into quad-packed LDS once.
__global__ __launch_bounds__(256) void stageC_kernel(const float* __restrict__ Vt,
                                                     float* __restrict__ out,
                                                     float* __restrict__ partial) {
  __shared__ float vq[2048];  // [j][4] = {b0t0, b1t0, b0t1, b1t1}
  int tpair = blockIdx.x >> 1;
  int lhalf = blockIdx.x & 1;
  int t0 = tpair << 1;
  int tid = threadIdx.x;
#pragma unroll
  for (int r = 0; r < 2; ++r) {
    int j = tid + (r << 8);
    const float* base = Vt + (j << 10);
    vq[(j << 2) + 0] = base[t0];
    vq[(j << 2) + 1] = base[512 + t0];
    vq[(j << 2) + 2] = base[t0 + 1];
    vq[(j << 2) + 3] = base[512 + t0 + 1];
  }
  __syncthreads();
  int l = (lhalf << 8) + tid;
  float t1 = __fmul_rn(PI_F, (float)(2 * l + 1));  // per-lane row factor
  // j = 0 peeled: Cy[0,l] = s0 * 2 * cos(0)
  float cy0 = __fmul_rn(1.0f / __fsqrt_rn(2048.0f), 2.0f);
  float4 v0 = *(const float4*)&vq[0];
  float a00 = __fmul_rn(cy0, v0.x);
  float a01 = __fmul_rn(cy0, v0.y);
  float a10 = __fmul_rn(cy0, v0.z);
  float a11 = __fmul_rn(cy0, v0.w);
#pragma unroll 8
  for (int j = 1; j < 512; ++j) {
    float arg = __fmul_rn(t1, (float)j) * (1.0f / 1024.0f);
    float c = __fmul_rn(0.0625f, __cosf(arg));  // = 0.03125*(2*cos), both muls exact
    float4 v = *(const float4*)&vq[j << 2];
    a00 = fmaf(c, v.x, a00);
    a01 = fmaf(c, v.y, a01);
    a10 = fmaf(c, v.z, a10);
    a11 = fmaf(c, v.w, a11);
  }
  float p00 = a00 / 3.0f, p01 = a01 / 3.0f, p10 = a10 / 3.0f, p11 = a11 / 3.0f;
  out[(t0 << 9) + l] = p00;
  out[((t0 + 1) << 9) + l] = p10;
  out[HALF_N + (t0 << 9) + l] = p01;
  out[HALF_N + ((t0 + 1) << 9) + l] = p11;
  float s0 = p00 + p10, q0 = fmaf(p00, p00, p10 * p10);
  float s1 = p01 + p11, q1 = fmaf(p01, p01, p11 * p11);
  for (int off = 32; off > 0; off >>= 1) {
    s0 += __shfl_down(s0, off);
    q0 += __shfl_down(q0, off);
    s1 += __shfl_down(s1, off);
    q1 += __shfl_down(q1, off);
  }
  __shared__ float red[4][4];
  int wave = tid >> 6;
  if ((tid & 63) == 0) {
    red[wave][0] = s0; red[wave][1] = q0; red[wave][2] = s1; red[wave][3] = q1;
  }
  __syncthreads();
  if (tid == 0) {
    float a0 = 0.f, a1 = 0.f, a2 = 0.f, a3 = 0.f;
    for (int wv = 0; wv < 4; ++wv) {
      a0 += red[wv][0]; a1 += red[wv][1]; a2 += red[wv][2]; a3 += red[wv][3];
    }
    partial[blockIdx.x * 4 + 0] = a0;
    partial[blockIdx.x * 4 + 1] = a1;
    partial[blockIdx.x * 4 + 2] = a2;
    partial[blockIdx.x * 4 + 3] = a3;
  }
}

// Fused stats + noise: every block redundantly reduces the 512x4 partials to
// (std0,std1), then adds JAX-threefry normal noise to its 256 output elements.
// element i -> threefry2x32(key=(0,42), ctr=(0,i)), bits = o0^o1
__global__ __launch_bounds__(256) void noise_kernel(float* __restrict__ out,
                                                    const float* __restrict__ partial) {
  int tid = threadIdx.x;
  const float4* pq = (const float4*)partial;  // 512 quads {s0,q0,s1,q1}
  float4 pa = pq[tid];
  float4 pb = pq[tid + 256];
  float s0 = pa.x + pb.x, q0 = pa.y + pb.y, s1 = pa.z + pb.z, q1 = pa.w + pb.w;
  for (int off = 32; off > 0; off >>= 1) {
    s0 += __shfl_down(s0, off);
    q0 += __shfl_down(q0, off);
    s1 += __shfl_down(s1, off);
    q1 += __shfl_down(q1, off);
  }
  __shared__ float red[4][4];
  int wave = tid >> 6;
  if ((tid & 63) == 0) {
    red[wave][0] = s0; red[wave][1] = q0; red[wave][2] = s1; red[wave][3] = q1;
  }
  __syncthreads();
  float S = red[0][0] + red[1][0] + red[2][0] + red[3][0];
  float Q = red[0][1] + red[1][1] + red[2][1] + red[3][1];
  float S2 = red[0][2] + red[1][2] + red[2][2] + red[3][2];
  float Q2 = red[0][3] + red[1][3] + red[2][3] + red[3][3];
  const float invN = 1.0f / 262144.0f;
  float m0 = S * invN, m1 = S2 * invN;
  float std0 = __fsqrt_rn(fmaxf(Q * invN - m0 * m0, 0.0f));
  float std1 = __fsqrt_rn(fmaxf(Q2 * invN - m1 * m1, 0.0f));

  int i = blockIdx.x * 256 + tid;  // < 524288
  uint32_t x0 = 0u;
  uint32_t x1 = (uint32_t)i;
  const uint32_t k0 = 0u, k1 = 42u;
  const uint32_t k2 = k0 ^ k1 ^ 0x1BD11BDAu;
  x0 += k0; x1 += k1;
#define QR(r) x0 += x1; x1 = rotl32(x1, r); x1 ^= x0;
  QR(13) QR(15) QR(26) QR(6)
  x0 += k1; x1 += k2 + 1u;
  QR(17) QR(29) QR(16) QR(24)
  x0 += k2; x1 += k0 + 2u;
  QR(13) QR(15) QR(26) QR(6)
  x0 += k0; x1 += k1 + 3u;
  QR(17) QR(29) QR(16) QR(24)
  x0 += k1; x1 += k2 + 4u;
  QR(13) QR(15) QR(26) QR(6)
  x0 += k2; x1 += k0 + 5u;
#undef QR
  uint32_t bits = x0 ^ x1;
  const float lo = __uint_as_float(0xBF7FFFFFu);  // nextafter(-1,0)
  float f = __uint_as_float((bits >> 9) | 0x3F800000u) - 1.0f;
  float u = fmaxf(lo, __fadd_rn(__fmul_rn(f, 2.0f), lo));
  const float sqrt2 = 1.41421356237309515f;
  out[i] += (i < HALF_N ? std0 : std1) * (sqrt2 * erfinv_xla(u));
}

extern "C" void kernel_launch(void* const* d_in, const int* in_sizes, int n_in,
                              void* d_out, int out_size, void* d_ws, size_t ws_size,
                              hipStream_t stream) {
  const float* x = (const float*)d_in[0];
  float* ws = (float*)d_ws;
  float* Vt      = ws;
  float* partial = ws + 524288;
  float* out = (float*)d_out;

  stageB_kernel<<<512, 512, 0, stream>>>(x, Vt);
  stageC_kernel<<<512, 256, 0, stream>>>(Vt, out, partial);
  noise_kernel<<<2048, 256, 0, stream>>>(out, partial);
}

// Round 9
// 128.895 us; speedup vs baseline: 1.4684x; 1.0229x over previous
//
#include <hip/hip_runtime.h>
#include <stdint.h>
#include <math.h>

// PhysicsForwardModel: B=2, Nz=Nx=128, Ly=Lx=512.
// out[b,t,l] = (1/3) * sum_j Cy[j,l] * sum_k cos(F[k,j]*t) * a[k] * (Cy[:,:128] x[b] Cy[:,128:256]^T)[k,j]
//              + std_b * N(0,1)  (JAX threefry key=42, partitionable counters, XLA erfinv)
// Cy/F recomputed on the fly via __cosf (pow2 scales exact -> op-order matches ref f32).
// R9: explicit 8-wide ILP in the t-scan (VGPR=20 in R8 serialized the cos chains).

#define HALF_N 262144  // 512*512 per-batch elements
#define PI_F 3.14159274101257324f

// ws layout (floats): Vt [0..524288) [j][b][t]; partial [524288..526336)

__device__ __forceinline__ uint32_t rotl32(uint32_t v, int r) {
  return (v << r) | (v >> (32 - r));
}

// XLA ErfInv32 (Giles) -- matches reference's lax.erf_inv
__device__ __forceinline__ float erfinv_xla(float x) {
  float w = -log1pf(__fmul_rn(-x, x));
  float p;
  if (w < 5.0f) {
    w = w - 2.5f;
    p = 2.81022636e-08f;
    p = fmaf(p, w, 3.43273939e-07f);
    p = fmaf(p, w, -3.5233877e-06f);
    p = fmaf(p, w, -4.39150654e-06f);
    p = fmaf(p, w, 0.00021858087f);
    p = fmaf(p, w, -0.00125372503f);
    p = fmaf(p, w, -0.00417768164f);
    p = fmaf(p, w, 0.246640727f);
    p = fmaf(p, w, 1.50140941f);
  } else {
    w = __fsqrt_rn(w) - 3.0f;
    p = -0.000200214257f;
    p = fmaf(p, w, 0.000100950558f);
    p = fmaf(p, w, 0.00134934322f);
    p = fmaf(p, w, -0.00367342844f);
    p = fmaf(p, w, 0.00573950773f);
    p = fmaf(p, w, -0.0076224613f);
    p = fmaf(p, w, 0.00943887047f);
    p = fmaf(p, w, 1.00167406f);
    p = fmaf(p, w, 2.83297682f);
  }
  return p * x;
}

// Cy[k,n] = sc(k) * 2 * cos(pi*(2n+1)*k/1024), with n2p1 = (float)(2n+1) exact
__device__ __forceinline__ float cy_elem(float n2p1, float kf, float sc) {
  float t1 = __fmul_rn(PI_F, n2p1);
  float arg = __fmul_rn(t1, kf) * (1.0f / 1024.0f);
  return __fmul_rn(sc, __fmul_rn(2.0f, __cosf(arg)));
}

// fusedB, block = j (grid 512, 512 threads):
//   A  (tid<128): cyl[jj] = Cy[j,128+jj]
//   A2 (tid<256): us[b*128+i] = sum_jj x[b,i,jj]*cyl[jj]
//   B  (lane=k):  msf[2k+b] = a[k] * sum_i Cy[k,i]*us[b,i]; fs[k] = F[k,j]
//   C  (lane=t):  Vt[j,b,t] = sum_k cos(fs[k]*t) * msf[2k+b]
__global__ __launch_bounds__(512, 4) void stageB_kernel(const float* __restrict__ x,
                                                        float* __restrict__ Vt) {
  __shared__ float cyl[128];
  __shared__ float us[256];
  __shared__ float fs[512];
  __shared__ float msf[1024];
  int j = blockIdx.x;
  int tid = threadIdx.x;
  float jf = (float)j;
  if (tid < 128) {
    float scj = (j == 0) ? (1.0f / __fsqrt_rn(2048.0f)) : 0.03125f;
    cyl[tid] = cy_elem((float)(2 * (128 + tid) + 1), jf, scj);
  }
  __syncthreads();
  if (tid < 256) {
    int b = tid >> 7, i = tid & 127;
    const float* xr = x + (b * 128 + i) * 128;
    float accA = 0.0f, accB = 0.0f;
    for (int jj = 0; jj < 128; jj += 8) {
      float4 xa = *(const float4*)&xr[jj];
      float4 xb = *(const float4*)&xr[jj + 4];
      float4 ca = *(const float4*)&cyl[jj];
      float4 cb = *(const float4*)&cyl[jj + 4];
      accA = fmaf(xa.x, ca.x, accA); accB = fmaf(xa.y, ca.y, accB);
      accA = fmaf(xa.z, ca.z, accA); accB = fmaf(xa.w, ca.w, accB);
      accA = fmaf(xb.x, cb.x, accA); accB = fmaf(xb.y, cb.y, accB);
      accA = fmaf(xb.z, cb.z, accA); accB = fmaf(xb.w, cb.w, accB);
    }
    us[tid] = accA + accB;
  }
  __syncthreads();
  {
    float kf = (float)tid;
    float sc = (tid == 0) ? (1.0f / __fsqrt_rn(2048.0f)) : 0.03125f;
    float a = cy_elem(1.0f, kf, sc);  // i=0: a[k] = Cy[k,0]
    float acc0 = __fmul_rn(a, us[0]);
    float acc1 = __fmul_rn(a, us[128]);
    // i = 1..3 singles, then aligned batches of 4
    float accA0 = 0.f, accA1 = 0.f;
    {
      float c1 = cy_elem(3.0f, kf, sc);
      float c2 = cy_elem(5.0f, kf, sc);
      float c3 = cy_elem(7.0f, kf, sc);
      acc0 = fmaf(c1, us[1], acc0);   acc1 = fmaf(c1, us[129], acc1);
      accA0 = fmaf(c2, us[2], accA0); accA1 = fmaf(c2, us[130], accA1);
      acc0 = fmaf(c3, us[3], acc0);   acc1 = fmaf(c3, us[131], acc1);
    }
    for (int i = 4; i < 128; i += 4) {
      float b0 = (float)(2 * i + 1);
      float c0 = cy_elem(b0, kf, sc);
      float c1 = cy_elem(__fadd_rn(b0, 2.0f), kf, sc);
      float c2 = cy_elem(__fadd_rn(b0, 4.0f), kf, sc);
      float c3 = cy_elem(__fadd_rn(b0, 6.0f), kf, sc);
      float4 u0 = *(const float4*)&us[i];
      float4 u1 = *(const float4*)&us[128 + i];
      acc0 = fmaf(c0, u0.x, acc0);   acc1 = fmaf(c0, u1.x, acc1);
      accA0 = fmaf(c1, u0.y, accA0); accA1 = fmaf(c1, u1.y, accA1);
      acc0 = fmaf(c2, u0.z, acc0);   acc1 = fmaf(c2, u1.z, acc1);
      accA0 = fmaf(c3, u0.w, accA0); accA1 = fmaf(c3, u1.w, accA1);
    }
    acc0 += accA0;
    acc1 += accA1;
    const float w0 = PI_F / 512.0f;  // exact pow2 scale of pi_f
    float ky = __fmul_rn(kf, w0);
    float kx = __fmul_rn(jf, w0);
    fs[tid] = __fsqrt_rn(__fadd_rn(__fmul_rn(ky, ky), __fmul_rn(kx, kx)));
    msf[2 * tid] = __fmul_rn(a, acc0);
    msf[2 * tid + 1] = __fmul_rn(a, acc1);
  }
  __syncthreads();
  float tf = (float)tid;
  float acc0 = 0.f, acc1 = 0.f, acc2 = 0.f, acc3 = 0.f;
  for (int k0 = 0; k0 < 512; k0 += 8) {
    float4 f0 = *(const float4*)&fs[k0];
    float4 f1 = *(const float4*)&fs[k0 + 4];
    float4 m0 = *(const float4*)&msf[2 * k0];
    float4 m1 = *(const float4*)&msf[2 * k0 + 4];
    float4 m2 = *(const float4*)&msf[2 * k0 + 8];
    float4 m3 = *(const float4*)&msf[2 * k0 + 12];
    float ph0 = __cosf(__fmul_rn(f0.x, tf));  // arg bit-matches ref's f32 F*t
    float ph1 = __cosf(__fmul_rn(f0.y, tf));
    float ph2 = __cosf(__fmul_rn(f0.z, tf));
    float ph3 = __cosf(__fmul_rn(f0.w, tf));
    float ph4 = __cosf(__fmul_rn(f1.x, tf));
    float ph5 = __cosf(__fmul_rn(f1.y, tf));
    float ph6 = __cosf(__fmul_rn(f1.z, tf));
    float ph7 = __cosf(__fmul_rn(f1.w, tf));
    acc0 = fmaf(ph0, m0.x, acc0); acc1 = fmaf(ph0, m0.y, acc1);
    acc2 = fmaf(ph1, m0.z, acc2); acc3 = fmaf(ph1, m0.w, acc3);
    acc0 = fmaf(ph2, m1.x, acc0); acc1 = fmaf(ph2, m1.y, acc1);
    acc2 = fmaf(ph3, m1.z, acc2); acc3 = fmaf(ph3, m1.w, acc3);
    acc0 = fmaf(ph4, m2.x, acc0); acc1 = fmaf(ph4, m2.y, acc1);
    acc2 = fmaf(ph5, m2.z, acc2); acc3 = fmaf(ph5, m2.w, acc3);
    acc0 = fmaf(ph6, m3.x, acc0); acc1 = fmaf(ph6, m3.y, acc1);
    acc2 = fmaf(ph7, m3.z, acc2); acc3 = fmaf(ph7, m3.w, acc3);
  }
  Vt[(j << 10) + tid] = acc0 + acc2;
  Vt[(j << 10) + 512 + tid] = acc1 + acc3;
}

// stageC: out[b,t,l] = (1/3) * sum_j Cy[j,l] * Vt[j,b,t]; Cy[j,l] on the fly.
__global__ __launch_bounds__(256, 4) void stageC_kernel(const float* __restrict__ Vt,
                                                        float* __restrict__ out,
                                                        float* __restrict__ partial) {
  __shared__ float vq[2048];  // [j][4] = {b0t0, b1t0, b0t1, b1t1}
  int tpair = blockIdx.x >> 1;
  int lhalf = blockIdx.x & 1;
  int t0 = tpair << 1;
  int tid = threadIdx.x;
#pragma unroll
  for (int r = 0; r < 2; ++r) {
    int j = tid + (r << 8);
    const float* base = Vt + (j << 10);
    vq[(j << 2) + 0] = base[t0];
    vq[(j << 2) + 1] = base[512 + t0];
    vq[(j << 2) + 2] = base[t0 + 1];
    vq[(j << 2) + 3] = base[512 + t0 + 1];
  }
  __syncthreads();
  int l = (lhalf << 8) + tid;
  float t1 = __fmul_rn(PI_F, (float)(2 * l + 1));
  float cy0 = __fmul_rn(1.0f / __fsqrt_rn(2048.0f), 2.0f);  // j=0: s0*2*cos(0)
  float4 v0 = *(const float4*)&vq[0];
  float a00 = __fmul_rn(cy0, v0.x);
  float a01 = __fmul_rn(cy0, v0.y);
  float a10 = __fmul_rn(cy0, v0.z);
  float a11 = __fmul_rn(cy0, v0.w);
  // j = 1..3 singles, then aligned batches of 4
  for (int j = 1; j < 4; ++j) {
    float arg = __fmul_rn(t1, (float)j) * (1.0f / 1024.0f);
    float c = __fmul_rn(0.0625f, __cosf(arg));
    float4 v = *(const float4*)&vq[j << 2];
    a00 = fmaf(c, v.x, a00);
    a01 = fmaf(c, v.y, a01);
    a10 = fmaf(c, v.z, a10);
    a11 = fmaf(c, v.w, a11);
  }
  for (int j = 4; j < 512; j += 4) {
    float jb = (float)j;
    float c0 = __fmul_rn(0.0625f, __cosf(__fmul_rn(t1, jb) * (1.0f / 1024.0f)));
    float c1 = __fmul_rn(0.0625f, __cosf(__fmul_rn(t1, __fadd_rn(jb, 1.0f)) * (1.0f / 1024.0f)));
    float c2 = __fmul_rn(0.0625f, __cosf(__fmul_rn(t1, __fadd_rn(jb, 2.0f)) * (1.0f / 1024.0f)));
    float c3 = __fmul_rn(0.0625f, __cosf(__fmul_rn(t1, __fadd_rn(jb, 3.0f)) * (1.0f / 1024.0f)));
    float4 va = *(const float4*)&vq[j << 2];
    float4 vb = *(const float4*)&vq[(j + 1) << 2];
    float4 vc = *(const float4*)&vq[(j + 2) << 2];
    float4 vd = *(const float4*)&vq[(j + 3) << 2];
    a00 = fmaf(c0, va.x, a00); a01 = fmaf(c0, va.y, a01);
    a10 = fmaf(c0, va.z, a10); a11 = fmaf(c0, va.w, a11);
    a00 = fmaf(c1, vb.x, a00); a01 = fmaf(c1, vb.y, a01);
    a10 = fmaf(c1, vb.z, a10); a11 = fmaf(c1, vb.w, a11);
    a00 = fmaf(c2, vc.x, a00); a01 = fmaf(c2, vc.y, a01);
    a10 = fmaf(c2, vc.z, a10); a11 = fmaf(c2, vc.w, a11);
    a00 = fmaf(c3, vd.x, a00); a01 = fmaf(c3, vd.y, a01);
    a10 = fmaf(c3, vd.z, a10); a11 = fmaf(c3, vd.w, a11);
  }
  float p00 = a00 / 3.0f, p01 = a01 / 3.0f, p10 = a10 / 3.0f, p11 = a11 / 3.0f;
  out[(t0 << 9) + l] = p00;
  out[((t0 + 1) << 9) + l] = p10;
  out[HALF_N + (t0 << 9) + l] = p01;
  out[HALF_N + ((t0 + 1) << 9) + l] = p11;
  float s0 = p00 + p10, q0 = fmaf(p00, p00, p10 * p10);
  float s1 = p01 + p11, q1 = fmaf(p01, p01, p11 * p11);
  for (int off = 32; off > 0; off >>= 1) {
    s0 += __shfl_down(s0, off);
    q0 += __shfl_down(q0, off);
    s1 += __shfl_down(s1, off);
    q1 += __shfl_down(q1, off);
  }
  __shared__ float red[4][4];
  int wave = tid >> 6;
  if ((tid & 63) == 0) {
    red[wave][0] = s0; red[wave][1] = q0; red[wave][2] = s1; red[wave][3] = q1;
  }
  __syncthreads();
  if (tid == 0) {
    float a0 = 0.f, a1 = 0.f, a2 = 0.f, a3 = 0.f;
    for (int wv = 0; wv < 4; ++wv) {
      a0 += red[wv][0]; a1 += red[wv][1]; a2 += red[wv][2]; a3 += red[wv][3];
    }
    partial[blockIdx.x * 4 + 0] = a0;
    partial[blockIdx.x * 4 + 1] = a1;
    partial[blockIdx.x * 4 + 2] = a2;
    partial[blockIdx.x * 4 + 3] = a3;
  }
}

// Fused stats + noise: redundant partial reduce -> (std0,std1), then threefry noise.
// element i -> threefry2x32(key=(0,42), ctr=(0,i)), bits = o0^o1
__global__ __launch_bounds__(256) void noise_kernel(float* __restrict__ out,
                                                    const float* __restrict__ partial) {
  int tid = threadIdx.x;
  const float4* pq = (const float4*)partial;  // 512 quads {s0,q0,s1,q1}
  float4 pa = pq[tid];
  float4 pb = pq[tid + 256];
  float s0 = pa.x + pb.x, q0 = pa.y + pb.y, s1 = pa.z + pb.z, q1 = pa.w + pb.w;
  for (int off = 32; off > 0; off >>= 1) {
    s0 += __shfl_down(s0, off);
    q0 += __shfl_down(q0, off);
    s1 += __shfl_down(s1, off);
    q1 += __shfl_down(q1, off);
  }
  __shared__ float red[4][4];
  int wave = tid >> 6;
  if ((tid & 63) == 0) {
    red[wave][0] = s0; red[wave][1] = q0; red[wave][2] = s1; red[wave][3] = q1;
  }
  __syncthreads();
  float S = red[0][0] + red[1][0] + red[2][0] + red[3][0];
  float Q = red[0][1] + red[1][1] + red[2][1] + red[3][1];
  float S2 = red[0][2] + red[1][2] + red[2][2] + red[3][2];
  float Q2 = red[0][3] + red[1][3] + red[2][3] + red[3][3];
  const float invN = 1.0f / 262144.0f;
  float m0 = S * invN, m1 = S2 * invN;
  float std0 = __fsqrt_rn(fmaxf(Q * invN - m0 * m0, 0.0f));
  float std1 = __fsqrt_rn(fmaxf(Q2 * invN - m1 * m1, 0.0f));

  int i = blockIdx.x * 256 + tid;  // < 524288
  uint32_t x0 = 0u;
  uint32_t x1 = (uint32_t)i;
  const uint32_t k0 = 0u, k1 = 42u;
  const uint32_t k2 = k0 ^ k1 ^ 0x1BD11BDAu;
  x0 += k0; x1 += k1;
#define QR(r) x0 += x1; x1 = rotl32(x1, r); x1 ^= x0;
  QR(13) QR(15) QR(26) QR(6)
  x0 += k1; x1 += k2 + 1u;
  QR(17) QR(29) QR(16) QR(24)
  x0 += k2; x1 += k0 + 2u;
  QR(13) QR(15) QR(26) QR(6)
  x0 += k0; x1 += k1 + 3u;
  QR(17) QR(29) QR(16) QR(24)
  x0 += k1; x1 += k2 + 4u;
  QR(13) QR(15) QR(26) QR(6)
  x0 += k2; x1 += k0 + 5u;
#undef QR
  uint32_t bits = x0 ^ x1;
  const float lo = __uint_as_float(0xBF7FFFFFu);  // nextafter(-1,0)
  float f = __uint_as_float((bits >> 9) | 0x3F800000u) - 1.0f;
  float u = fmaxf(lo, __fadd_rn(__fmul_rn(f, 2.0f), lo));
  const float sqrt2 = 1.41421356237309515f;
  out[i] += (i < HALF_N ? std0 : std1) * (sqrt2 * erfinv_xla(u));
}

extern "C" void kernel_launch(void* const* d_in, const int* in_sizes, int n_in,
                              void* d_out, int out_size, void* d_ws, size_t ws_size,
                              hipStream_t stream) {
  const float* x = (const float*)d_in[0];
  float* ws = (float*)d_ws;
  float* Vt      = ws;
  float* partial = ws + 524288;
  float* out = (float*)d_out;

  stageB_kernel<<<512, 512, 0, stream>>>(x, Vt);
  stageC_kernel<<<512, 256, 0, stream>>>(Vt, out, partial);
  noise_kernel<<<2048, 256, 0, stream>>>(out, partial);
}